// Round 1
// baseline (10405.876 us; speedup 1.0000x reference)
//
#include <hip/hip_runtime.h>
#include <math.h>

#define NN   10000
#define NE   80000
#define NG   64
#define HID  256
#define RBFK 16
#define NDEP 6
#define KA   16
#define KC   6
#define KE   5
#define DE   85
#define CATW 784

static __device__ __forceinline__ float silu_f(float v) { return v / (1.0f + expf(-v)); }

// ---------------- tiny precompute: gather tables ----------------
__global__ void tables_kernel(const float* __restrict__ atom_W, const float* __restrict__ charge_W,
                              const float* __restrict__ bond_W, const float* __restrict__ fuse_W,
                              const float* __restrict__ fuse_b, const float* __restrict__ lift_W,
                              const float* __restrict__ lift_b,
                              float* __restrict__ tabA, float* __restrict__ tabC, float* __restrict__ tabE) {
  int k = threadIdx.x;  // 256
  for (int r = 0; r < KA; ++r) {
    float s = 0.f;
    for (int d = 0; d < DE; ++d) s += atom_W[r*DE + d] * fuse_W[d*HID + k];
    tabA[r*HID + k] = s + fuse_b[k];
  }
  for (int r = 0; r < KC; ++r) {
    float s = 0.f;
    for (int d = 0; d < DE; ++d) s += charge_W[r*DE + d] * fuse_W[(DE + d)*HID + k];
    tabC[r*HID + k] = s;
  }
  for (int r = 0; r < KE; ++r) {
    float s = 0.f;
    for (int d = 0; d < DE; ++d) s += bond_W[r*DE + d] * lift_W[d*HID + k];
    tabE[r*HID + k] = s + lift_b[k];
  }
}

// ---------------- node init: argmax embed + copy x ----------------
__global__ void node_init_kernel(const float* __restrict__ a_t, const float* __restrict__ c_t,
                                 const float* __restrict__ g_a, const float* __restrict__ g_c,
                                 const float* __restrict__ x_t, const float* __restrict__ tabA,
                                 const float* __restrict__ tabC, float* __restrict__ h,
                                 float* __restrict__ x) {
  int n = blockIdx.x;
  __shared__ int s_ia, s_ic;
  if (threadIdx.x == 0) {
    float best = -1e30f; int bi = 0;
    for (int j = 0; j < KA; ++j) {
      float v = logf(fmaxf(a_t[n*KA + j], 1e-12f)) + g_a[n*KA + j];
      if (v > best) { best = v; bi = j; }
    }
    s_ia = bi;
  }
  if (threadIdx.x == 1) {
    float best = -1e30f; int bi = 0;
    for (int j = 0; j < KC; ++j) {
      float v = logf(fmaxf(c_t[n*KC + j], 1e-12f)) + g_c[n*KC + j];
      if (v > best) { best = v; bi = j; }
    }
    s_ic = bi;
  }
  __syncthreads();
  int k = threadIdx.x;
  h[n*HID + k] = tabA[s_ia*HID + k] + tabC[s_ic*HID + k];
  if (k < 3) x[n*3 + k] = x_t[n*3 + k];
}

__global__ void edge_init_kernel(const float* __restrict__ e_t, const float* __restrict__ g_e,
                                 int* __restrict__ ie) {
  int e = blockIdx.x * blockDim.x + threadIdx.x;
  if (e >= NE) return;
  float best = -1e30f; int bi = 0;
  for (int j = 0; j < KE; ++j) {
    float v = logf(fmaxf(e_t[e*KE + j], 1e-12f)) + g_e[e*KE + j];
    if (v > best) { best = v; bi = j; }
  }
  ie[e] = bi;
}

// ---------------- per-depth: rij + rbf ----------------
__global__ void rbf_kernel(const float* __restrict__ x, const int* __restrict__ srcp,
                           const int* __restrict__ dstp, float* __restrict__ rij,
                           float* __restrict__ rbfb) {
  int e = blockIdx.x * blockDim.x + threadIdx.x;
  if (e >= NE) return;
  int s = srcp[e], d = dstp[e];
  float r0 = x[d*3+0] - x[s*3+0];
  float r1 = x[d*3+1] - x[s*3+1];
  float r2 = x[d*3+2] - x[s*3+2];
  rij[e*3+0] = r0; rij[e*3+1] = r1; rij[e*3+2] = r2;
  float dist = sqrtf(r0*r0 + r1*r1 + r2*r2);
#pragma unroll
  for (int k = 0; k < RBFK; ++k) {
    float c = (10.0f/15.0f) * (float)k;
    float z = (dist - c) / (0.625f + 1e-12f);
    rbfb[e*RBFK + k] = expf(-0.5f * z * z);
  }
}

// ---------------- tiled fp32 GEMM, C[M x 256] = act(A[M x K] @ W[K x 256] + b) ----------------
// MODE 0: A plain (row stride = K)
// MODE 1: A = cat(e) = [h[dst], h[src], rbf, tabE[ie]]   (K = 784)
// MODE 2: A = [h[m], pm_sum[m]]                          (K = 512)
#define BM 64
#define BN 64
#define BK 16

template<int MODE, bool SILU_OUT>
__global__ __launch_bounds__(256) void gemm_kernel(
    const float* __restrict__ A, const float* __restrict__ W,
    const float* __restrict__ bias, float* __restrict__ C, int M, int K,
    const float* __restrict__ h, const float* __restrict__ pm,
    const float* __restrict__ rbfb, const float* __restrict__ tabE,
    const int* __restrict__ ie, const int* __restrict__ srcp, const int* __restrict__ dstp) {
  __shared__ float As[BK][BM + 4];   // transposed: As[k][m]
  __shared__ float Ws[BK][BN + 4];
  const int bn = blockIdx.x * BN;
  const int bm = blockIdx.y * BM;
  const int tid = threadIdx.x;
  const int tx = tid & 15, ty = tid >> 4;
  const int arow = tid >> 2;         // 0..63 (m within tile)
  const int akq  = (tid & 3) * 4;    // k offset 0,4,8,12
  const int wrow = tid >> 4;         // 0..15
  const int wcol = (tid & 15) * 4;   // 0..60
  const int m = bm + arow;
  int g_dst = 0, g_src = 0, g_ie = 0;
  if (MODE == 1 && m < M) { g_dst = dstp[m]; g_src = srcp[m]; g_ie = ie[m]; }
  float acc[4][4] = {};
  for (int k0 = 0; k0 < K; k0 += BK) {
#pragma unroll
    for (int i = 0; i < 4; ++i) {
      int k = k0 + akq + i;
      float v = 0.f;
      if (m < M) {
        if (MODE == 0) {
          v = A[(size_t)m*K + k];
        } else if (MODE == 1) {
          if (k < 256)      v = h[(size_t)g_dst*HID + k];
          else if (k < 512) v = h[(size_t)g_src*HID + (k - 256)];
          else if (k < 528) v = rbfb[(size_t)m*RBFK + (k - 512)];
          else              v = tabE[(size_t)g_ie*HID + (k - 528)];
        } else {
          v = (k < 256) ? h[(size_t)m*HID + k] : pm[(size_t)m*HID + (k - 256)];
        }
      }
      As[akq + i][arow] = v;
    }
#pragma unroll
    for (int i = 0; i < 4; ++i)
      Ws[wrow][wcol + i] = W[(size_t)(k0 + wrow)*HID + bn + wcol + i];
    __syncthreads();
#pragma unroll
    for (int kk = 0; kk < BK; ++kk) {
      float4 a = *reinterpret_cast<const float4*>(&As[kk][ty*4]);
      float4 b = *reinterpret_cast<const float4*>(&Ws[kk][tx*4]);
      float av[4] = {a.x, a.y, a.z, a.w};
      float bv[4] = {b.x, b.y, b.z, b.w};
#pragma unroll
      for (int i = 0; i < 4; ++i)
#pragma unroll
        for (int j = 0; j < 4; ++j)
          acc[i][j] += av[i] * bv[j];
    }
    __syncthreads();
  }
#pragma unroll
  for (int i = 0; i < 4; ++i) {
    int mrow = bm + ty*4 + i;
    if (mrow < M) {
#pragma unroll
      for (int j = 0; j < 4; ++j) {
        int n = bn + tx*4 + j;
        float v = acc[i][j] + bias[n];
        if (SILU_OUT) v = silu_f(v);
        C[(size_t)mrow*HID + n] = v;
      }
    }
  }
}

// ---------------- gate: E x 256 @ 256 x 1 ----------------
__global__ void gate_kernel(const float* __restrict__ A, const float* __restrict__ W,
                            const float* __restrict__ b, float* __restrict__ gate) {
  int e = blockIdx.x * 4 + (threadIdx.x >> 6);
  int lane = threadIdx.x & 63;
  if (e >= NE) return;
  float s = 0.f;
#pragma unroll
  for (int j = 0; j < 4; ++j) s += A[(size_t)e*HID + lane + j*64] * W[lane + j*64];
#pragma unroll
  for (int off = 32; off > 0; off >>= 1) s += __shfl_down(s, off, 64);
  if (lane == 0) gate[e] = s + b[0];
}

// ---------------- scatter to dst ----------------
__global__ void scatter_kernel(const float* __restrict__ pm, const float* __restrict__ gate,
                               const float* __restrict__ rij, const int* __restrict__ dstp,
                               float* __restrict__ pm_sum, float* __restrict__ dxacc) {
  int e = blockIdx.x;
  int k = threadIdx.x;
  int dn = dstp[e];
  atomicAdd(&pm_sum[(size_t)dn*HID + k], pm[(size_t)e*HID + k]);
  if (k < 3) atomicAdd(&dxacc[dn*3 + k], rij[e*3 + k] * gate[e]);
}

__global__ void x_update_kernel(float* __restrict__ x, const float* __restrict__ dxacc) {
  int i = blockIdx.x * blockDim.x + threadIdx.x;
  if (i < NN*3) x[i] += dxacc[i];
}

// ---------------- LayerNorm(h + u) ----------------
__global__ void ln_kernel(float* __restrict__ h, const float* __restrict__ u,
                          const float* __restrict__ g, const float* __restrict__ b) {
  int n = blockIdx.x;
  int k = threadIdx.x;
  int lane = k & 63, wv = k >> 6;
  float z = h[(size_t)n*HID + k] + u[(size_t)n*HID + k];
  __shared__ float red[4];
  __shared__ float s_mu, s_rstd;
  float s = z;
#pragma unroll
  for (int off = 32; off > 0; off >>= 1) s += __shfl_down(s, off, 64);
  if (lane == 0) red[wv] = s;
  __syncthreads();
  if (k == 0) s_mu = (red[0] + red[1] + red[2] + red[3]) * (1.0f/HID);
  __syncthreads();
  float d = z - s_mu;
  float s2 = d * d;
#pragma unroll
  for (int off = 32; off > 0; off >>= 1) s2 += __shfl_down(s2, off, 64);
  if (lane == 0) red[wv] = s2;
  __syncthreads();
  if (k == 0) s_rstd = 1.0f / sqrtf((red[0] + red[1] + red[2] + red[3]) * (1.0f/HID) + 1e-5f);
  __syncthreads();
  h[(size_t)n*HID + k] = d * s_rstd * g[k] + b[k];
}

// ---------------- readout ----------------
__global__ void graph_acc_kernel(const float* __restrict__ h, const int* __restrict__ ng,
                                 float* __restrict__ hg, float* __restrict__ cnt) {
  int n = blockIdx.x, k = threadIdx.x;
  int g = ng[n];
  atomicAdd(&hg[(size_t)g*HID + k], h[(size_t)n*HID + k]);
  if (k == 0) atomicAdd(&cnt[g], 1.0f);
}

__global__ void head_kernel(const float* __restrict__ hg, const float* __restrict__ cnt,
                            const float* __restrict__ head_W, const float* __restrict__ head_b,
                            float* __restrict__ out) {
  int g = threadIdx.x;
  if (g >= NG) return;
  float dot = 0.f;
  for (int k = 0; k < HID; ++k) dot += hg[(size_t)g*HID + k] * head_W[k];
  float c = fmaxf(cnt[g], 1.0f);
  float v = (dot / c + head_b[0]) * 0.5f;
  out[g] = 1.0f / (1.0f + expf(-v));
}

extern "C" void kernel_launch(void* const* d_in, const int* in_sizes, int n_in,
                              void* d_out, int out_size, void* d_ws, size_t ws_size,
                              hipStream_t stream) {
  (void)in_sizes; (void)n_in; (void)out_size; (void)ws_size;
  const float* a_t      = (const float*)d_in[0];
  const float* c_t      = (const float*)d_in[1];
  const float* e_t      = (const float*)d_in[2];
  const float* x_t      = (const float*)d_in[3];
  const float* g_a      = (const float*)d_in[4];
  const float* g_c      = (const float*)d_in[5];
  const float* g_e      = (const float*)d_in[6];
  const float* atom_W   = (const float*)d_in[7];
  const float* charge_W = (const float*)d_in[8];
  const float* bond_W   = (const float*)d_in[9];
  const float* fuse_W   = (const float*)d_in[10];
  const float* fuse_b   = (const float*)d_in[11];
  const float* lift_W   = (const float*)d_in[12];
  const float* lift_b   = (const float*)d_in[13];
  const float* phim_W1  = (const float*)d_in[14];
  const float* phim_b1  = (const float*)d_in[15];
  const float* phim_W2  = (const float*)d_in[16];
  const float* phim_b2  = (const float*)d_in[17];
  const float* phix_W1  = (const float*)d_in[18];
  const float* phix_b1  = (const float*)d_in[19];
  const float* phix_W2  = (const float*)d_in[20];
  const float* phix_b2  = (const float*)d_in[21];
  const float* psim_W1  = (const float*)d_in[22];
  const float* psim_b1  = (const float*)d_in[23];
  const float* psim_W2  = (const float*)d_in[24];
  const float* psim_b2  = (const float*)d_in[25];
  const float* updh_W1  = (const float*)d_in[26];
  const float* updh_b1  = (const float*)d_in[27];
  const float* updh_W2  = (const float*)d_in[28];
  const float* updh_b2  = (const float*)d_in[29];
  const float* ln_g     = (const float*)d_in[30];
  const float* ln_b     = (const float*)d_in[31];
  const float* head_W   = (const float*)d_in[32];
  const float* head_b   = (const float*)d_in[33];
  const int*   src      = (const int*)d_in[34];
  const int*   dst      = (const int*)d_in[35];
  const int*   ngraph   = (const int*)d_in[36];
  float* out = (float*)d_out;

  char* p = (char*)d_ws;
  auto carve = [&](size_t bytes) -> char* {
    char* r = p; p += (bytes + 255) & ~(size_t)255; return r;
  };
  float* h      = (float*)carve((size_t)NN*HID*4);
  float* xpos   = (float*)carve((size_t)NN*3*4);
  int*   ie     = (int*)  carve((size_t)NE*4);
  float* tabA   = (float*)carve((size_t)KA*HID*4);
  float* tabC   = (float*)carve((size_t)KC*HID*4);
  float* tabE   = (float*)carve((size_t)KE*HID*4);
  float* rbfb   = (float*)carve((size_t)NE*RBFK*4);
  float* rij    = (float*)carve((size_t)NE*3*4);
  float* gate   = (float*)carve((size_t)NE*4);
  size_t pmdx_bytes = (size_t)NN*HID*4 + (size_t)NN*3*4;
  float* pm_sum = (float*)carve(pmdx_bytes);
  float* dxacc  = pm_sum + (size_t)NN*HID;
  size_t hg_bytes = (size_t)NG*HID*4 + (size_t)NG*4;
  float* hg     = (float*)carve(hg_bytes);
  float* cnt    = hg + (size_t)NG*HID;
  float* bufA   = (float*)carve((size_t)NE*HID*4);
  float* bufB   = (float*)carve((size_t)NE*HID*4);

  tables_kernel<<<1, 256, 0, stream>>>(atom_W, charge_W, bond_W, fuse_W, fuse_b, lift_W, lift_b,
                                       tabA, tabC, tabE);
  node_init_kernel<<<NN, 256, 0, stream>>>(a_t, c_t, g_a, g_c, x_t, tabA, tabC, h, xpos);
  edge_init_kernel<<<(NE + 255)/256, 256, 0, stream>>>(e_t, g_e, ie);

  dim3 gridE(HID/BN, (NE + BM - 1)/BM);
  dim3 gridN(HID/BN, (NN + BM - 1)/BM);

  for (int d = 0; d < NDEP; ++d) {
    const float* pW1m = phim_W1 + (size_t)d*CATW*HID;
    const float* pb1m = phim_b1 + (size_t)d*HID;
    const float* pW2m = phim_W2 + (size_t)d*HID*HID;
    const float* pb2m = phim_b2 + (size_t)d*HID;
    const float* pxW1 = phix_W1 + (size_t)d*HID*HID;
    const float* pxb1 = phix_b1 + (size_t)d*HID;
    const float* pxW2 = phix_W2 + (size_t)d*HID;
    const float* pxb2 = phix_b2 + (size_t)d;
    const float* psW1 = psim_W1 + (size_t)d*CATW*HID;
    const float* psb1 = psim_b1 + (size_t)d*HID;
    const float* psW2 = psim_W2 + (size_t)d*HID*HID;
    const float* psb2 = psim_b2 + (size_t)d*HID;
    const float* puW1 = updh_W1 + (size_t)d*2*HID*HID;
    const float* pub1 = updh_b1 + (size_t)d*HID;
    const float* puW2 = updh_W2 + (size_t)d*HID*HID;
    const float* pub2 = updh_b2 + (size_t)d*HID;

    rbf_kernel<<<(NE + 255)/256, 256, 0, stream>>>(xpos, src, dst, rij, rbfb);
    hipMemsetAsync(pm_sum, 0, pmdx_bytes, stream);

    // bufA = silu(cat @ phim_W1 + b1)
    gemm_kernel<1, true><<<gridE, 256, 0, stream>>>(nullptr, pW1m, pb1m, bufA, NE, CATW,
                                                    h, nullptr, rbfb, tabE, ie, src, dst);
    // bufB = m = silu(bufA @ phim_W2 + b2)
    gemm_kernel<0, true><<<gridE, 256, 0, stream>>>(bufA, pW2m, pb2m, bufB, NE, HID,
                                                    nullptr, nullptr, nullptr, nullptr, nullptr, nullptr, nullptr);
    // bufA = silu(m @ phix_W1 + b1)
    gemm_kernel<0, true><<<gridE, 256, 0, stream>>>(bufB, pxW1, pxb1, bufA, NE, HID,
                                                    nullptr, nullptr, nullptr, nullptr, nullptr, nullptr, nullptr);
    // gate = bufA @ phix_W2 + b2
    gate_kernel<<<NE/4, 256, 0, stream>>>(bufA, pxW2, pxb2, gate);
    // bufA = silu(cat @ psim_W1 + b1)
    gemm_kernel<1, true><<<gridE, 256, 0, stream>>>(nullptr, psW1, psb1, bufA, NE, CATW,
                                                    h, nullptr, rbfb, tabE, ie, src, dst);
    // bufB = pm = silu(bufA @ psim_W2 + b2)
    gemm_kernel<0, true><<<gridE, 256, 0, stream>>>(bufA, psW2, psb2, bufB, NE, HID,
                                                    nullptr, nullptr, nullptr, nullptr, nullptr, nullptr, nullptr);
    // scatter pm and gated rij to dst
    scatter_kernel<<<NE, 256, 0, stream>>>(bufB, gate, rij, dst, pm_sum, dxacc);
    // bufA(first NN rows) = silu([h, pm_sum] @ updh_W1 + b1)
    gemm_kernel<2, true><<<gridN, 256, 0, stream>>>(nullptr, puW1, pub1, bufA, NN, 2*HID,
                                                    h, pm_sum, nullptr, nullptr, nullptr, nullptr, nullptr);
    // bufB(first NN rows) = u = bufA @ updh_W2 + b2
    gemm_kernel<0, false><<<gridN, 256, 0, stream>>>(bufA, puW2, pub2, bufB, NN, HID,
                                                     nullptr, nullptr, nullptr, nullptr, nullptr, nullptr, nullptr);
    x_update_kernel<<<(NN*3 + 255)/256, 256, 0, stream>>>(xpos, dxacc);
    ln_kernel<<<NN, 256, 0, stream>>>(h, bufB, ln_g + (size_t)d*HID, ln_b + (size_t)d*HID);
  }

  hipMemsetAsync(hg, 0, hg_bytes, stream);
  graph_acc_kernel<<<NN, 256, 0, stream>>>(h, ngraph, hg, cnt);
  head_kernel<<<1, 64, 0, stream>>>(hg, cnt, head_W, head_b, out);
}

// Round 2
// 3201.340 us; speedup vs baseline: 3.2505x; 3.2505x over previous
//
#include <hip/hip_runtime.h>
#include <math.h>

#define NN   10000
#define NE   80000
#define NG   64
#define HID  256
#define RBFK 16
#define NDEP 6
#define KA   16
#define KC   6
#define KE   5
#define DE   85
#define CATW 784
#define CATP 800   // padded to multiple of 32

typedef __attribute__((ext_vector_type(8))) short bf16x8;
typedef __attribute__((ext_vector_type(4))) float f32x4;

static __device__ __forceinline__ float silu_f(float v) { return v / (1.0f + expf(-v)); }

static __device__ __forceinline__ unsigned short f2bf(float f) {
  union { float f; unsigned int u; } v; v.f = f;
  unsigned int r = v.u + 0x7fff + ((v.u >> 16) & 1);
  return (unsigned short)(r >> 16);
}
static __device__ __forceinline__ float bf2f(unsigned short h) {
  union { unsigned int u; float f; } v; v.u = ((unsigned int)h) << 16;
  return v.f;
}

// ---------------- weight convert: fp32 [D][K][256] -> bf16 transposed [D][256][Kp] ----------------
// permute=1: cat-row permutation (new order: h_dst, h_src, e_emb, rbf, zero-pad)
__global__ void convw_kernel(const float* __restrict__ W, unsigned short* __restrict__ Wt,
                             int K, int Kp, int total, int permute) {
  int idx = blockIdx.x * 256 + threadIdx.x;
  if (idx >= total) return;
  int per = 256 * Kp;
  int d = idx / per;
  int rem = idx - d * per;
  int n = rem / Kp;
  int k = rem - n * Kp;
  int ko;
  if (permute) ko = (k < 512) ? k : (k < 768 ? k + 16 : (k < 784 ? k - 256 : -1));
  else ko = (k < K) ? k : -1;
  float v = 0.f;
  if (ko >= 0) v = W[(size_t)d * K * 256 + (size_t)ko * 256 + n];
  Wt[idx] = f2bf(v);
}

// ---------------- tables ----------------
__global__ void tables_kernel(const float* __restrict__ atom_W, const float* __restrict__ charge_W,
                              const float* __restrict__ bond_W, const float* __restrict__ fuse_W,
                              const float* __restrict__ fuse_b, const float* __restrict__ lift_W,
                              const float* __restrict__ lift_b,
                              float* __restrict__ tabA, float* __restrict__ tabC,
                              unsigned short* __restrict__ tabE) {
  int k = threadIdx.x;  // 256
  for (int r = 0; r < KA; ++r) {
    float s = 0.f;
    for (int d = 0; d < DE; ++d) s += atom_W[r*DE + d] * fuse_W[d*HID + k];
    tabA[r*HID + k] = s + fuse_b[k];
  }
  for (int r = 0; r < KC; ++r) {
    float s = 0.f;
    for (int d = 0; d < DE; ++d) s += charge_W[r*DE + d] * fuse_W[(DE + d)*HID + k];
    tabC[r*HID + k] = s;
  }
  for (int r = 0; r < KE; ++r) {
    float s = 0.f;
    for (int d = 0; d < DE; ++d) s += bond_W[r*DE + d] * lift_W[d*HID + k];
    tabE[r*HID + k] = f2bf(s + lift_b[k]);
  }
}

// ---------------- node init ----------------
__global__ void node_init_kernel(const float* __restrict__ a_t, const float* __restrict__ c_t,
                                 const float* __restrict__ g_a, const float* __restrict__ g_c,
                                 const float* __restrict__ x_t, const float* __restrict__ tabA,
                                 const float* __restrict__ tabC, float* __restrict__ h,
                                 unsigned short* __restrict__ hbf, float* __restrict__ x) {
  int n = blockIdx.x;
  __shared__ int s_ia, s_ic;
  if (threadIdx.x == 0) {
    float best = -1e30f; int bi = 0;
    for (int j = 0; j < KA; ++j) {
      float v = logf(fmaxf(a_t[n*KA + j], 1e-12f)) + g_a[n*KA + j];
      if (v > best) { best = v; bi = j; }
    }
    s_ia = bi;
  }
  if (threadIdx.x == 1) {
    float best = -1e30f; int bi = 0;
    for (int j = 0; j < KC; ++j) {
      float v = logf(fmaxf(c_t[n*KC + j], 1e-12f)) + g_c[n*KC + j];
      if (v > best) { best = v; bi = j; }
    }
    s_ic = bi;
  }
  __syncthreads();
  int k = threadIdx.x;
  float v = tabA[s_ia*HID + k] + tabC[s_ic*HID + k];
  h[n*HID + k] = v;
  hbf[n*HID + k] = f2bf(v);
  if (k < 3) x[n*3 + k] = x_t[n*3 + k];
}

__global__ void edge_init_kernel(const float* __restrict__ e_t, const float* __restrict__ g_e,
                                 int* __restrict__ ie) {
  int e = blockIdx.x * blockDim.x + threadIdx.x;
  if (e >= NE) return;
  float best = -1e30f; int bi = 0;
  for (int j = 0; j < KE; ++j) {
    float v = logf(fmaxf(e_t[e*KE + j], 1e-12f)) + g_e[e*KE + j];
    if (v > best) { best = v; bi = j; }
  }
  ie[e] = bi;
}

// ---------------- per-depth: rij + rbf(bf16) ----------------
__global__ void rbf_kernel(const float* __restrict__ x, const int* __restrict__ srcp,
                           const int* __restrict__ dstp, float* __restrict__ rij,
                           unsigned short* __restrict__ rbfb) {
  int e = blockIdx.x * blockDim.x + threadIdx.x;
  if (e >= NE) return;
  int s = srcp[e], d = dstp[e];
  float r0 = x[d*3+0] - x[s*3+0];
  float r1 = x[d*3+1] - x[s*3+1];
  float r2 = x[d*3+2] - x[s*3+2];
  rij[e*3+0] = r0; rij[e*3+1] = r1; rij[e*3+2] = r2;
  float dist = sqrtf(r0*r0 + r1*r1 + r2*r2);
#pragma unroll
  for (int k = 0; k < RBFK; ++k) {
    float c = (10.0f/15.0f) * (float)k;
    float z = (dist - c) / (0.625f + 1e-12f);
    rbfb[e*RBFK + k] = f2bf(expf(-0.5f * z * z));
  }
}

// ---------------- MFMA bf16 GEMM: C[M x 256] = act(A[M x Kp] @ W + b), bf16 out ----------------
// MODE 0: A = bf16 [M][256]
// MODE 1: A = cat(e) = [h[dst] | h[src] | tabE[ie] | rbf | pad]  (Kp = 800)
// MODE 2: A = [h | pm]  (Kp = 512)
template<int MODE, bool SILU>
__global__ __launch_bounds__(256) void mfma_gemm(
    const unsigned short* __restrict__ A, const unsigned short* __restrict__ A2,
    const unsigned short* __restrict__ Wt,   // [256][Kp] (transposed, permuted, padded)
    const float* __restrict__ bias, unsigned short* __restrict__ C,
    int M, int Kp,
    const unsigned short* __restrict__ hbf, const unsigned short* __restrict__ tabE,
    const int* __restrict__ srcp, const int* __restrict__ dstp, const int* __restrict__ iep) {
  __shared__ unsigned short As[128][40];
  __shared__ unsigned short Bs[128][40];
  __shared__ int sidx[3][128];
  const int tid = threadIdx.x;
  const int bn = blockIdx.x * 128;
  const int bm = blockIdx.y * 128;
  const int lane = tid & 63;
  const int wid = tid >> 6;
  const int wr = wid >> 1, wc = wid & 1;

  if (MODE == 1 && tid < 128) {
    int m = bm + tid; if (m >= M) m = M - 1;
    sidx[0][tid] = dstp[m];
    sidx[1][tid] = srcp[m];
    sidx[2][tid] = iep[m];
  }
  if (MODE == 1) __syncthreads();

  f32x4 acc[4][4] = {};

  for (int k0 = 0; k0 < Kp; k0 += 32) {
#pragma unroll
    for (int i = 0; i < 2; ++i) {
      int l = tid + i * 256;
      int r = l >> 2;
      int seg = (l & 3) * 8;
      int m = bm + r;
      uint4 v = make_uint4(0u, 0u, 0u, 0u);
      if (MODE == 0) {
        if (m < M) v = *(const uint4*)&A[(size_t)m*256 + k0 + seg];
      } else if (MODE == 1) {
        int k = k0 + seg;
        if (k < 256)      v = *(const uint4*)&hbf[(size_t)sidx[0][r]*256 + k];
        else if (k < 512) v = *(const uint4*)&hbf[(size_t)sidx[1][r]*256 + (k - 256)];
        else if (k < 768) v = *(const uint4*)&tabE[(size_t)sidx[2][r]*256 + (k - 512)];
        else if (k < 784) v = *(const uint4*)&A2[(size_t)m*RBFK + (k - 768)];
      } else {
        if (m < M) {
          int k = k0 + seg;
          v = (k < 256) ? *(const uint4*)&A[(size_t)m*256 + k]
                        : *(const uint4*)&A2[(size_t)m*256 + (k - 256)];
        }
      }
      *(uint4*)&As[r][seg] = v;
      uint4 w = *(const uint4*)&Wt[(size_t)(bn + r)*Kp + k0 + seg];
      *(uint4*)&Bs[r][seg] = w;
    }
    __syncthreads();
    bf16x8 af[4], bfr[4];
#pragma unroll
    for (int i = 0; i < 4; ++i)
      af[i] = *(const bf16x8*)&As[wr*64 + i*16 + (lane & 15)][(lane >> 4) * 8];
#pragma unroll
    for (int j = 0; j < 4; ++j)
      bfr[j] = *(const bf16x8*)&Bs[wc*64 + j*16 + (lane & 15)][(lane >> 4) * 8];
#pragma unroll
    for (int i = 0; i < 4; ++i)
#pragma unroll
      for (int j = 0; j < 4; ++j)
        acc[i][j] = __builtin_amdgcn_mfma_f32_16x16x32_bf16(af[i], bfr[j], acc[i][j], 0, 0, 0);
    __syncthreads();
  }

  const int colbase = bn + wc*64 + (lane & 15);
#pragma unroll
  for (int j = 0; j < 4; ++j) {
    int col = colbase + j*16;
    float bv = bias[col];
#pragma unroll
    for (int i = 0; i < 4; ++i) {
      int row0 = bm + wr*64 + i*16 + (lane >> 4) * 4;
#pragma unroll
      for (int q = 0; q < 4; ++q) {
        int row = row0 + q;
        if (row < M) {
          float v = acc[i][j][q] + bv;
          if (SILU) v = silu_f(v);
          C[(size_t)row*256 + col] = f2bf(v);
        }
      }
    }
  }
}

// ---------------- gate: E x 256 @ 256 x 1 ----------------
__global__ void gate_kernel(const unsigned short* __restrict__ A, const float* __restrict__ W,
                            const float* __restrict__ b, float* __restrict__ gate) {
  int e = blockIdx.x * 4 + (threadIdx.x >> 6);
  int lane = threadIdx.x & 63;
  if (e >= NE) return;
  float s = 0.f;
#pragma unroll
  for (int j = 0; j < 4; ++j) s += bf2f(A[(size_t)e*HID + lane + j*64]) * W[lane + j*64];
#pragma unroll
  for (int off = 32; off > 0; off >>= 1) s += __shfl_down(s, off, 64);
  if (lane == 0) gate[e] = s + b[0];
}

// ---------------- scatter to dst ----------------
__global__ void scatter_kernel(const unsigned short* __restrict__ pm, const float* __restrict__ gate,
                               const float* __restrict__ rij, const int* __restrict__ dstp,
                               float* __restrict__ pm_sum, float* __restrict__ dxacc) {
  int e = blockIdx.x;
  int k = threadIdx.x;
  int dn = dstp[e];
  atomicAdd(&pm_sum[(size_t)dn*HID + k], bf2f(pm[(size_t)e*HID + k]));
  if (k < 3) atomicAdd(&dxacc[dn*3 + k], rij[e*3 + k] * gate[e]);
}

__global__ void pm2bf_kernel(const float* __restrict__ pm_sum, unsigned short* __restrict__ pmbf) {
  int i = blockIdx.x * 256 + threadIdx.x;
  if (i < NN*HID) pmbf[i] = f2bf(pm_sum[i]);
}

__global__ void x_update_kernel(float* __restrict__ x, const float* __restrict__ dxacc) {
  int i = blockIdx.x * blockDim.x + threadIdx.x;
  if (i < NN*3) x[i] += dxacc[i];
}

// ---------------- LayerNorm(h + u) ----------------
__global__ void ln_kernel(float* __restrict__ h, unsigned short* __restrict__ hbf,
                          const unsigned short* __restrict__ u,
                          const float* __restrict__ g, const float* __restrict__ b) {
  int n = blockIdx.x;
  int k = threadIdx.x;
  int lane = k & 63, wv = k >> 6;
  float z = h[(size_t)n*HID + k] + bf2f(u[(size_t)n*HID + k]);
  __shared__ float red[4];
  __shared__ float s_mu, s_rstd;
  float s = z;
#pragma unroll
  for (int off = 32; off > 0; off >>= 1) s += __shfl_down(s, off, 64);
  if (lane == 0) red[wv] = s;
  __syncthreads();
  if (k == 0) s_mu = (red[0] + red[1] + red[2] + red[3]) * (1.0f/HID);
  __syncthreads();
  float d = z - s_mu;
  float s2 = d * d;
#pragma unroll
  for (int off = 32; off > 0; off >>= 1) s2 += __shfl_down(s2, off, 64);
  if (lane == 0) red[wv] = s2;
  __syncthreads();
  if (k == 0) s_rstd = 1.0f / sqrtf((red[0] + red[1] + red[2] + red[3]) * (1.0f/HID) + 1e-5f);
  __syncthreads();
  float o = d * s_rstd * g[k] + b[k];
  h[(size_t)n*HID + k] = o;
  hbf[(size_t)n*HID + k] = f2bf(o);
}

// ---------------- readout ----------------
__global__ void graph_acc_kernel(const float* __restrict__ h, const int* __restrict__ ng,
                                 float* __restrict__ hg, float* __restrict__ cnt) {
  int n = blockIdx.x, k = threadIdx.x;
  int g = ng[n];
  atomicAdd(&hg[(size_t)g*HID + k], h[(size_t)n*HID + k]);
  if (k == 0) atomicAdd(&cnt[g], 1.0f);
}

__global__ void head_kernel(const float* __restrict__ hg, const float* __restrict__ cnt,
                            const float* __restrict__ head_W, const float* __restrict__ head_b,
                            float* __restrict__ out) {
  int g = threadIdx.x;
  if (g >= NG) return;
  float dot = 0.f;
  for (int k = 0; k < HID; ++k) dot += hg[(size_t)g*HID + k] * head_W[k];
  float c = fmaxf(cnt[g], 1.0f);
  float v = (dot / c + head_b[0]) * 0.5f;
  out[g] = 1.0f / (1.0f + expf(-v));
}

extern "C" void kernel_launch(void* const* d_in, const int* in_sizes, int n_in,
                              void* d_out, int out_size, void* d_ws, size_t ws_size,
                              hipStream_t stream) {
  (void)in_sizes; (void)n_in; (void)out_size; (void)ws_size;
  const float* a_t      = (const float*)d_in[0];
  const float* c_t      = (const float*)d_in[1];
  const float* e_t      = (const float*)d_in[2];
  const float* x_t      = (const float*)d_in[3];
  const float* g_a      = (const float*)d_in[4];
  const float* g_c      = (const float*)d_in[5];
  const float* g_e      = (const float*)d_in[6];
  const float* atom_W   = (const float*)d_in[7];
  const float* charge_W = (const float*)d_in[8];
  const float* bond_W   = (const float*)d_in[9];
  const float* fuse_W   = (const float*)d_in[10];
  const float* fuse_b   = (const float*)d_in[11];
  const float* lift_W   = (const float*)d_in[12];
  const float* lift_b   = (const float*)d_in[13];
  const float* phim_W1  = (const float*)d_in[14];
  const float* phim_b1  = (const float*)d_in[15];
  const float* phim_W2  = (const float*)d_in[16];
  const float* phim_b2  = (const float*)d_in[17];
  const float* phix_W1  = (const float*)d_in[18];
  const float* phix_b1  = (const float*)d_in[19];
  const float* phix_W2  = (const float*)d_in[20];
  const float* phix_b2  = (const float*)d_in[21];
  const float* psim_W1  = (const float*)d_in[22];
  const float* psim_b1  = (const float*)d_in[23];
  const float* psim_W2  = (const float*)d_in[24];
  const float* psim_b2  = (const float*)d_in[25];
  const float* updh_W1  = (const float*)d_in[26];
  const float* updh_b1  = (const float*)d_in[27];
  const float* updh_W2  = (const float*)d_in[28];
  const float* updh_b2  = (const float*)d_in[29];
  const float* ln_g     = (const float*)d_in[30];
  const float* ln_b     = (const float*)d_in[31];
  const float* head_W   = (const float*)d_in[32];
  const float* head_b   = (const float*)d_in[33];
  const int*   src      = (const int*)d_in[34];
  const int*   dst      = (const int*)d_in[35];
  const int*   ngraph   = (const int*)d_in[36];
  float* out = (float*)d_out;

  char* p = (char*)d_ws;
  auto carve = [&](size_t bytes) -> char* {
    char* r = p; p += (bytes + 255) & ~(size_t)255; return r;
  };
  float*          h     = (float*)carve((size_t)NN*HID*4);
  unsigned short* hbf   = (unsigned short*)carve((size_t)NN*HID*2);
  float*          xpos  = (float*)carve((size_t)NN*3*4);
  int*            ie    = (int*)carve((size_t)NE*4);
  float*          tabA  = (float*)carve((size_t)KA*HID*4);
  float*          tabC  = (float*)carve((size_t)KC*HID*4);
  unsigned short* tabE  = (unsigned short*)carve((size_t)KE*HID*2);
  unsigned short* rbfb  = (unsigned short*)carve((size_t)NE*RBFK*2);
  float*          rij   = (float*)carve((size_t)NE*3*4);
  float*          gate  = (float*)carve((size_t)NE*4);
  size_t pmdx_bytes = (size_t)NN*HID*4 + (size_t)NN*3*4;
  float*          pm_sum = (float*)carve(pmdx_bytes);
  float*          dxacc  = pm_sum + (size_t)NN*HID;
  unsigned short* pmbf   = (unsigned short*)carve((size_t)NN*HID*2);
  size_t hg_bytes = (size_t)NG*HID*4 + (size_t)NG*4;
  float*          hg    = (float*)carve(hg_bytes);
  float*          cnt   = hg + (size_t)NG*HID;
  unsigned short* bufA  = (unsigned short*)carve((size_t)NE*HID*2);
  unsigned short* bufB  = (unsigned short*)carve((size_t)NE*HID*2);
  // transposed bf16 weights
  unsigned short* wPhim1 = (unsigned short*)carve((size_t)NDEP*HID*CATP*2);
  unsigned short* wPsim1 = (unsigned short*)carve((size_t)NDEP*HID*CATP*2);
  unsigned short* wPhim2 = (unsigned short*)carve((size_t)NDEP*HID*HID*2);
  unsigned short* wPhix1 = (unsigned short*)carve((size_t)NDEP*HID*HID*2);
  unsigned short* wPsim2 = (unsigned short*)carve((size_t)NDEP*HID*HID*2);
  unsigned short* wUpd1  = (unsigned short*)carve((size_t)NDEP*HID*512*2);
  unsigned short* wUpd2  = (unsigned short*)carve((size_t)NDEP*HID*HID*2);

  // ---- weight conversion (per call) ----
  {
    int tot1 = NDEP*HID*CATP;
    convw_kernel<<<(tot1+255)/256, 256, 0, stream>>>(phim_W1, wPhim1, CATW, CATP, tot1, 1);
    convw_kernel<<<(tot1+255)/256, 256, 0, stream>>>(psim_W1, wPsim1, CATW, CATP, tot1, 1);
    int tot2 = NDEP*HID*HID;
    convw_kernel<<<(tot2+255)/256, 256, 0, stream>>>(phim_W2, wPhim2, HID, HID, tot2, 0);
    convw_kernel<<<(tot2+255)/256, 256, 0, stream>>>(phix_W1, wPhix1, HID, HID, tot2, 0);
    convw_kernel<<<(tot2+255)/256, 256, 0, stream>>>(psim_W2, wPsim2, HID, HID, tot2, 0);
    convw_kernel<<<(tot2+255)/256, 256, 0, stream>>>(updh_W2, wUpd2, HID, HID, tot2, 0);
    int tot3 = NDEP*HID*512;
    convw_kernel<<<(tot3+255)/256, 256, 0, stream>>>(updh_W1, wUpd1, 512, 512, tot3, 0);
  }

  tables_kernel<<<1, 256, 0, stream>>>(atom_W, charge_W, bond_W, fuse_W, fuse_b, lift_W, lift_b,
                                       tabA, tabC, tabE);
  node_init_kernel<<<NN, 256, 0, stream>>>(a_t, c_t, g_a, g_c, x_t, tabA, tabC, h, hbf, xpos);
  edge_init_kernel<<<(NE + 255)/256, 256, 0, stream>>>(e_t, g_e, ie);

  dim3 gridE(2, (NE + 127)/128);
  dim3 gridN(2, (NN + 127)/128);

  for (int d = 0; d < NDEP; ++d) {
    const float* pb1m = phim_b1 + (size_t)d*HID;
    const float* pb2m = phim_b2 + (size_t)d*HID;
    const float* pxb1 = phix_b1 + (size_t)d*HID;
    const float* pxW2 = phix_W2 + (size_t)d*HID;
    const float* pxb2 = phix_b2 + (size_t)d;
    const float* psb1 = psim_b1 + (size_t)d*HID;
    const float* psb2 = psim_b2 + (size_t)d*HID;
    const float* pub1 = updh_b1 + (size_t)d*HID;
    const float* pub2 = updh_b2 + (size_t)d*HID;

    rbf_kernel<<<(NE + 255)/256, 256, 0, stream>>>(xpos, src, dst, rij, rbfb);
    hipMemsetAsync(pm_sum, 0, pmdx_bytes, stream);

    // bufA = silu(cat @ phim_W1 + b1)
    mfma_gemm<1, true><<<gridE, 256, 0, stream>>>(nullptr, rbfb, wPhim1 + (size_t)d*HID*CATP,
                                                  pb1m, bufA, NE, CATP, hbf, tabE, src, dst, ie);
    // bufB = m = silu(bufA @ phim_W2 + b2)
    mfma_gemm<0, true><<<gridE, 256, 0, stream>>>(bufA, nullptr, wPhim2 + (size_t)d*HID*HID,
                                                  pb2m, bufB, NE, HID, nullptr, nullptr, nullptr, nullptr, nullptr);
    // bufA = silu(m @ phix_W1 + b1)
    mfma_gemm<0, true><<<gridE, 256, 0, stream>>>(bufB, nullptr, wPhix1 + (size_t)d*HID*HID,
                                                  pxb1, bufA, NE, HID, nullptr, nullptr, nullptr, nullptr, nullptr);
    // gate = bufA @ phix_W2 + b2
    gate_kernel<<<NE/4, 256, 0, stream>>>(bufA, pxW2, pxb2, gate);
    // bufA = silu(cat @ psim_W1 + b1)
    mfma_gemm<1, true><<<gridE, 256, 0, stream>>>(nullptr, rbfb, wPsim1 + (size_t)d*HID*CATP,
                                                  psb1, bufA, NE, CATP, hbf, tabE, src, dst, ie);
    // bufB = pm = silu(bufA @ psim_W2 + b2)
    mfma_gemm<0, true><<<gridE, 256, 0, stream>>>(bufA, nullptr, wPsim2 + (size_t)d*HID*HID,
                                                  psb2, bufB, NE, HID, nullptr, nullptr, nullptr, nullptr, nullptr);
    // scatter pm and gated rij to dst
    scatter_kernel<<<NE, 256, 0, stream>>>(bufB, gate, rij, dst, pm_sum, dxacc);
    pm2bf_kernel<<<(NN*HID + 255)/256, 256, 0, stream>>>(pm_sum, pmbf);
    // bufA(first NN rows) = silu([h, pm_sum] @ updh_W1 + b1)
    mfma_gemm<2, true><<<gridN, 256, 0, stream>>>(hbf, pmbf, wUpd1 + (size_t)d*HID*512,
                                                  pub1, bufA, NN, 512, nullptr, nullptr, nullptr, nullptr, nullptr);
    // bufB(first NN rows) = u = bufA @ updh_W2 + b2
    mfma_gemm<0, false><<<gridN, 256, 0, stream>>>(bufA, nullptr, wUpd2 + (size_t)d*HID*HID,
                                                   pub2, bufB, NN, HID, nullptr, nullptr, nullptr, nullptr, nullptr);
    x_update_kernel<<<(NN*3 + 255)/256, 256, 0, stream>>>(xpos, dxacc);
    ln_kernel<<<NN, 256, 0, stream>>>(h, hbf, bufB, ln_g + (size_t)d*HID, ln_b + (size_t)d*HID);
  }

  hipMemsetAsync(hg, 0, hg_bytes, stream);
  graph_acc_kernel<<<NN, 256, 0, stream>>>(h, ngraph, hg, cnt);
  head_kernel<<<1, 64, 0, stream>>>(hg, cnt, head_W, head_b, out);
}

// Round 3
// 2607.486 us; speedup vs baseline: 3.9908x; 1.2277x over previous
//
#include <hip/hip_runtime.h>
#include <math.h>

#define NN   10000
#define NE   80000
#define NG   64
#define HID  256
#define RBFK 16
#define NDEP 6
#define KA   16
#define KC   6
#define KE   5
#define DE   85
#define CATW 784
#define CATP 800   // padded to multiple of 32

typedef __attribute__((ext_vector_type(8))) short bf16x8;
typedef __attribute__((ext_vector_type(4))) float f32x4;

static __device__ __forceinline__ float silu_f(float v) { return v / (1.0f + expf(-v)); }

static __device__ __forceinline__ unsigned short f2bf(float f) {
  union { float f; unsigned int u; } v; v.f = f;
  unsigned int r = v.u + 0x7fff + ((v.u >> 16) & 1);
  return (unsigned short)(r >> 16);
}
static __device__ __forceinline__ float bf2f(unsigned short h) {
  union { unsigned int u; float f; } v; v.u = ((unsigned int)h) << 16;
  return v.f;
}

// ---------------- LDS-tiled weight transpose-convert ----------------
// plain: W [D][K][256] f32 -> Wt [D][256][K] bf16
__global__ void convw_plain(const float* __restrict__ W, unsigned short* __restrict__ Wt, int K) {
  __shared__ float T[32][65];
  int k0 = blockIdx.x * 32, n0 = blockIdx.y * 64, d = blockIdx.z;
  int tid = threadIdx.x;
  int nn = tid & 63, kr = tid >> 6;
  const float* Wd = W + (size_t)d * K * 256;
#pragma unroll
  for (int i = 0; i < 8; ++i) {
    int k = kr + i * 4;
    T[k][nn] = Wd[(size_t)(k0 + k) * 256 + n0 + nn];
  }
  __syncthreads();
  unsigned short* Wtd = Wt + (size_t)d * 256 * K;
  int kk = tid & 31, nr = tid >> 5;
#pragma unroll
  for (int i = 0; i < 8; ++i) {
    int n = nr + i * 8;
    Wtd[(size_t)(n0 + n) * K + k0 + kk] = f2bf(T[kk][n]);
  }
}

// cat: W [D][784][256] f32 -> Wt [D][512][800] bf16 rows [ro, ro+256)
// permuted k-order: [h_dst 0..511 | e_emb 512..767 | rbf 768..783 | pad]
__global__ void convw_cat(const float* __restrict__ W, unsigned short* __restrict__ Wt, int ro) {
  __shared__ float T[32][65];
  int k0 = blockIdx.x * 32, n0 = blockIdx.y * 64, d = blockIdx.z;
  int tid = threadIdx.x;
  int nn = tid & 63, kr = tid >> 6;
  const float* Wd = W + (size_t)d * CATW * 256;
#pragma unroll
  for (int i = 0; i < 8; ++i) {
    int k = k0 + kr + i * 4;
    int ko = (k < 512) ? k : (k < 768 ? k + 16 : (k < 784 ? k - 256 : -1));
    T[kr + i*4][nn] = (ko >= 0) ? Wd[(size_t)ko * 256 + n0 + nn] : 0.f;
  }
  __syncthreads();
  unsigned short* Wtd = Wt + (size_t)d * 512 * CATP;
  int kk = tid & 31, nr = tid >> 5;
#pragma unroll
  for (int i = 0; i < 8; ++i) {
    int n = nr + i * 8;
    Wtd[(size_t)(ro + n0 + n) * CATP + k0 + kk] = f2bf(T[kk][n]);
  }
}

// ---------------- tables (27 blocks) ----------------
__global__ void tables_kernel(const float* __restrict__ atom_W, const float* __restrict__ charge_W,
                              const float* __restrict__ bond_W, const float* __restrict__ fuse_W,
                              const float* __restrict__ fuse_b, const float* __restrict__ lift_W,
                              const float* __restrict__ lift_b,
                              float* __restrict__ tabA, float* __restrict__ tabC,
                              unsigned short* __restrict__ tabE) {
  int r = blockIdx.x, k = threadIdx.x;
  if (r < KA) {
    float s = 0.f;
    for (int d = 0; d < DE; ++d) s += atom_W[r*DE + d] * fuse_W[d*HID + k];
    tabA[r*HID + k] = s + fuse_b[k];
  } else if (r < KA + KC) {
    int rr = r - KA;
    float s = 0.f;
    for (int d = 0; d < DE; ++d) s += charge_W[rr*DE + d] * fuse_W[(DE + d)*HID + k];
    tabC[rr*HID + k] = s;
  } else {
    int rr = r - KA - KC;
    float s = 0.f;
    for (int d = 0; d < DE; ++d) s += bond_W[rr*DE + d] * lift_W[d*HID + k];
    tabE[rr*HID + k] = f2bf(s + lift_b[k]);
  }
}

// ---------------- node / edge init ----------------
__global__ void node_init_kernel(const float* __restrict__ a_t, const float* __restrict__ c_t,
                                 const float* __restrict__ g_a, const float* __restrict__ g_c,
                                 const float* __restrict__ x_t, const float* __restrict__ tabA,
                                 const float* __restrict__ tabC, float* __restrict__ h,
                                 unsigned short* __restrict__ hbf, float* __restrict__ x) {
  int n = blockIdx.x;
  __shared__ int s_ia, s_ic;
  if (threadIdx.x == 0) {
    float best = -1e30f; int bi = 0;
    for (int j = 0; j < KA; ++j) {
      float v = logf(fmaxf(a_t[n*KA + j], 1e-12f)) + g_a[n*KA + j];
      if (v > best) { best = v; bi = j; }
    }
    s_ia = bi;
  }
  if (threadIdx.x == 1) {
    float best = -1e30f; int bi = 0;
    for (int j = 0; j < KC; ++j) {
      float v = logf(fmaxf(c_t[n*KC + j], 1e-12f)) + g_c[n*KC + j];
      if (v > best) { best = v; bi = j; }
    }
    s_ic = bi;
  }
  __syncthreads();
  int k = threadIdx.x;
  float v = tabA[s_ia*HID + k] + tabC[s_ic*HID + k];
  h[n*HID + k] = v;
  hbf[n*HID + k] = f2bf(v);
  if (k < 3) x[n*3 + k] = x_t[n*3 + k];
}

__global__ void edge_init_kernel(const float* __restrict__ e_t, const float* __restrict__ g_e,
                                 int* __restrict__ ie) {
  int e = blockIdx.x * blockDim.x + threadIdx.x;
  if (e >= NE) return;
  float best = -1e30f; int bi = 0;
  for (int j = 0; j < KE; ++j) {
    float v = logf(fmaxf(e_t[e*KE + j], 1e-12f)) + g_e[e*KE + j];
    if (v > best) { best = v; bi = j; }
  }
  ie[e] = bi;
}

// ---------------- CSR build (per call; deterministic via per-row sort) ----------------
__global__ void hist_kernel(const int* __restrict__ dst, int* __restrict__ deg) {
  int e = blockIdx.x * 256 + threadIdx.x;
  if (e < NE) atomicAdd(&deg[dst[e]], 1);
}

__global__ void scan_kernel(const int* __restrict__ deg, int* __restrict__ rowstart,
                            int* __restrict__ cursor) {
  __shared__ int tmp[1024];
  int t = threadIdx.x;
  int base = t * 10;
  int local[10];
  int s = 0;
#pragma unroll
  for (int i = 0; i < 10; ++i) { local[i] = deg[base + i]; s += local[i]; }
  tmp[t] = s;
  __syncthreads();
  for (int off = 1; off < 1024; off <<= 1) {
    int v = (t >= off) ? tmp[t - off] : 0;
    __syncthreads();
    tmp[t] += v;
    __syncthreads();
  }
  int run = (t == 0) ? 0 : tmp[t - 1];
#pragma unroll
  for (int i = 0; i < 10; ++i) {
    rowstart[base + i] = run; cursor[base + i] = run; run += local[i];
  }
  if (t == 1023) rowstart[10240] = run;
}

__global__ void fill_kernel(const int* __restrict__ dst, int* __restrict__ cursor,
                            int* __restrict__ eids) {
  int e = blockIdx.x * 256 + threadIdx.x;
  if (e >= NE) return;
  int pos = atomicAdd(&cursor[dst[e]], 1);
  eids[pos] = e;
}

__global__ void sortrows_kernel(const int* __restrict__ rowstart, int* __restrict__ eids) {
  int n = blockIdx.x * 256 + threadIdx.x;
  if (n >= NN) return;
  int s = rowstart[n], e = rowstart[n + 1];
  for (int i = s + 1; i < e; ++i) {
    int v = eids[i]; int j = i - 1;
    while (j >= s && eids[j] > v) { eids[j + 1] = eids[j]; --j; }
    eids[j + 1] = v;
  }
}

// ---------------- per-depth: rij + rbf(bf16) ----------------
__global__ void rbf_kernel(const float* __restrict__ x, const int* __restrict__ srcp,
                           const int* __restrict__ dstp, float* __restrict__ rij,
                           unsigned short* __restrict__ rbfb) {
  int e = blockIdx.x * blockDim.x + threadIdx.x;
  if (e >= NE) return;
  int s = srcp[e], d = dstp[e];
  float r0 = x[d*3+0] - x[s*3+0];
  float r1 = x[d*3+1] - x[s*3+1];
  float r2 = x[d*3+2] - x[s*3+2];
  rij[e*3+0] = r0; rij[e*3+1] = r1; rij[e*3+2] = r2;
  float dist = sqrtf(r0*r0 + r1*r1 + r2*r2);
#pragma unroll
  for (int k = 0; k < RBFK; ++k) {
    float c = (10.0f/15.0f) * (float)k;
    float z = (dist - c) / (0.625f + 1e-12f);
    rbfb[e*RBFK + k] = f2bf(expf(-0.5f * z * z));
  }
}

// ---------------- MFMA bf16 GEMM ----------------
// MODE 0: A bf16 [M][256]
// MODE 1: A = cat(e) = [h[dst] | h[src] | tabE[ie] | rbf | pad] (Kp=800, N=512 dual-output)
// MODE 2: A = [hbf | pmbf] (Kp=512)
// GATE:   no C store; gate[row] += sum_col silu(acc+b1[col]) * gw2[col]  (atomics)
template<int MODE, bool SILU, bool GATE>
__global__ __launch_bounds__(256) void mfma_gemm(
    const unsigned short* __restrict__ A, const unsigned short* __restrict__ A2,
    const unsigned short* __restrict__ Wt,
    const float* __restrict__ bias, const float* __restrict__ bias2,
    unsigned short* __restrict__ C, unsigned short* __restrict__ C2,
    int M, int Kp,
    const unsigned short* __restrict__ hbf, const unsigned short* __restrict__ tabE,
    const int* __restrict__ srcp, const int* __restrict__ dstp, const int* __restrict__ iep,
    const float* __restrict__ gw2, float* __restrict__ gout) {
  __shared__ unsigned short As[128][40];
  __shared__ unsigned short Bs[128][40];
  __shared__ int sidx[3][128];
  const int tid = threadIdx.x;
  const int bn = blockIdx.x * 128;
  const int bm = blockIdx.y * 128;
  const int lane = tid & 63;
  const int wid = tid >> 6;
  const int wr = wid >> 1, wc = wid & 1;

  if (MODE == 1 && tid < 128) {
    int m = bm + tid; if (m >= M) m = M - 1;
    sidx[0][tid] = dstp[m];
    sidx[1][tid] = srcp[m];
    sidx[2][tid] = iep[m];
  }
  if (MODE == 1) __syncthreads();

  f32x4 acc[4][4] = {};

  for (int k0 = 0; k0 < Kp; k0 += 32) {
#pragma unroll
    for (int i = 0; i < 2; ++i) {
      int l = tid + i * 256;
      int r = l >> 2;
      int seg = (l & 3) * 8;
      int m = bm + r;
      uint4 v = make_uint4(0u, 0u, 0u, 0u);
      if (MODE == 0) {
        if (m < M) v = *(const uint4*)&A[(size_t)m*256 + k0 + seg];
      } else if (MODE == 1) {
        int k = k0 + seg;
        if (k < 256)      v = *(const uint4*)&hbf[(size_t)sidx[0][r]*256 + k];
        else if (k < 512) v = *(const uint4*)&hbf[(size_t)sidx[1][r]*256 + (k - 256)];
        else if (k < 768) v = *(const uint4*)&tabE[(size_t)sidx[2][r]*256 + (k - 512)];
        else if (k < 784) v = *(const uint4*)&A2[(size_t)m*RBFK + (k - 768)];
      } else {
        if (m < M) {
          int k = k0 + seg;
          v = (k < 256) ? *(const uint4*)&A[(size_t)m*256 + k]
                        : *(const uint4*)&A2[(size_t)m*256 + (k - 256)];
        }
      }
      *(uint4*)&As[r][seg] = v;
      uint4 w = *(const uint4*)&Wt[(size_t)(bn + r)*Kp + k0 + seg];
      *(uint4*)&Bs[r][seg] = w;
    }
    __syncthreads();
    bf16x8 af[4], bfr[4];
#pragma unroll
    for (int i = 0; i < 4; ++i)
      af[i] = *(const bf16x8*)&As[wr*64 + i*16 + (lane & 15)][(lane >> 4) * 8];
#pragma unroll
    for (int j = 0; j < 4; ++j)
      bfr[j] = *(const bf16x8*)&Bs[wc*64 + j*16 + (lane & 15)][(lane >> 4) * 8];
#pragma unroll
    for (int i = 0; i < 4; ++i)
#pragma unroll
      for (int j = 0; j < 4; ++j)
        acc[i][j] = __builtin_amdgcn_mfma_f32_16x16x32_bf16(af[i], bfr[j], acc[i][j], 0, 0, 0);
    __syncthreads();
  }

  if (GATE) {
    float bcol[4], wcol[4];
#pragma unroll
    for (int j = 0; j < 4; ++j) {
      int col = bn + wc*64 + j*16 + (lane & 15);
      bcol[j] = bias[col];
      wcol[j] = gw2[col];
    }
#pragma unroll
    for (int i = 0; i < 4; ++i) {
#pragma unroll
      for (int q = 0; q < 4; ++q) {
        float lsum = 0.f;
#pragma unroll
        for (int j = 0; j < 4; ++j)
          lsum += silu_f(acc[i][j][q] + bcol[j]) * wcol[j];
        lsum += __shfl_xor(lsum, 1, 64);
        lsum += __shfl_xor(lsum, 2, 64);
        lsum += __shfl_xor(lsum, 4, 64);
        lsum += __shfl_xor(lsum, 8, 64);
        if ((lane & 15) == 0) {
          int row = bm + wr*64 + i*16 + ((lane >> 4) << 2) + q;
          if (row < M) atomicAdd(&gout[row], lsum);
        }
      }
    }
    return;
  }

  const float* biasw = bias;
  unsigned short* Cw = C;
  int cb = bn;
  if (MODE == 1 && bn >= 256) { biasw = bias2; Cw = C2; cb = bn - 256; }

  const int colbase = cb + wc*64 + (lane & 15);
#pragma unroll
  for (int j = 0; j < 4; ++j) {
    int col = colbase + j*16;
    float bv = biasw[col];
#pragma unroll
    for (int i = 0; i < 4; ++i) {
      int row0 = bm + wr*64 + i*16 + (lane >> 4) * 4;
#pragma unroll
      for (int q = 0; q < 4; ++q) {
        int row = row0 + q;
        if (row < M) {
          float v = acc[i][j][q] + bv;
          if (SILU) v = silu_f(v);
          Cw[(size_t)row*256 + col] = f2bf(v);
        }
      }
    }
  }
}

// ---------------- CSR gather: pm_sum (bf16 out) + dx + x update ----------------
__global__ void gather_pm_dx(const unsigned short* __restrict__ pm, const float* __restrict__ gate,
                             const float* __restrict__ rij, const int* __restrict__ rowstart,
                             const int* __restrict__ eids, const float* __restrict__ gb2,
                             unsigned short* __restrict__ pmbf, float* __restrict__ x) {
  int n = blockIdx.x, k = threadIdx.x;
  int s = rowstart[n], e1 = rowstart[n + 1];
  float acc = 0.f, dx = 0.f;
  float b2 = gb2[0];
  for (int t = s; t < e1; ++t) {
    int e = eids[t];
    acc += bf2f(pm[(size_t)e*HID + k]);
    if (k < 3) dx += rij[e*3 + k] * (gate[e] + b2);
  }
  pmbf[(size_t)n*HID + k] = f2bf(acc);
  if (k < 3) x[n*3 + k] += dx;
}

// ---------------- LayerNorm(h + u) ----------------
__global__ void ln_kernel(float* __restrict__ h, unsigned short* __restrict__ hbf,
                          const unsigned short* __restrict__ u,
                          const float* __restrict__ g, const float* __restrict__ b) {
  int n = blockIdx.x;
  int k = threadIdx.x;
  int lane = k & 63, wv = k >> 6;
  float z = h[(size_t)n*HID + k] + bf2f(u[(size_t)n*HID + k]);
  __shared__ float red[4];
  __shared__ float s_mu, s_rstd;
  float s = z;
#pragma unroll
  for (int off = 32; off > 0; off >>= 1) s += __shfl_down(s, off, 64);
  if (lane == 0) red[wv] = s;
  __syncthreads();
  if (k == 0) s_mu = (red[0] + red[1] + red[2] + red[3]) * (1.0f/HID);
  __syncthreads();
  float d = z - s_mu;
  float s2 = d * d;
#pragma unroll
  for (int off = 32; off > 0; off >>= 1) s2 += __shfl_down(s2, off, 64);
  if (lane == 0) red[wv] = s2;
  __syncthreads();
  if (k == 0) s_rstd = 1.0f / sqrtf((red[0] + red[1] + red[2] + red[3]) * (1.0f/HID) + 1e-5f);
  __syncthreads();
  float o = d * s_rstd * g[k] + b[k];
  h[(size_t)n*HID + k] = o;
  hbf[(size_t)n*HID + k] = f2bf(o);
}

// ---------------- readout ----------------
__global__ void graph_acc_kernel(const float* __restrict__ h, const int* __restrict__ ng,
                                 float* __restrict__ hg, float* __restrict__ cnt) {
  int n = blockIdx.x, k = threadIdx.x;
  int g = ng[n];
  atomicAdd(&hg[(size_t)g*HID + k], h[(size_t)n*HID + k]);
  if (k == 0) atomicAdd(&cnt[g], 1.0f);
}

__global__ void head_kernel(const float* __restrict__ hg, const float* __restrict__ cnt,
                            const float* __restrict__ head_W, const float* __restrict__ head_b,
                            float* __restrict__ out) {
  int g = threadIdx.x;
  if (g >= NG) return;
  float dot = 0.f;
  for (int k = 0; k < HID; ++k) dot += hg[(size_t)g*HID + k] * head_W[k];
  float c = fmaxf(cnt[g], 1.0f);
  float v = (dot / c + head_b[0]) * 0.5f;
  out[g] = 1.0f / (1.0f + expf(-v));
}

extern "C" void kernel_launch(void* const* d_in, const int* in_sizes, int n_in,
                              void* d_out, int out_size, void* d_ws, size_t ws_size,
                              hipStream_t stream) {
  (void)in_sizes; (void)n_in; (void)out_size; (void)ws_size;
  const float* a_t      = (const float*)d_in[0];
  const float* c_t      = (const float*)d_in[1];
  const float* e_t      = (const float*)d_in[2];
  const float* x_t      = (const float*)d_in[3];
  const float* g_a      = (const float*)d_in[4];
  const float* g_c      = (const float*)d_in[5];
  const float* g_e      = (const float*)d_in[6];
  const float* atom_W   = (const float*)d_in[7];
  const float* charge_W = (const float*)d_in[8];
  const float* bond_W   = (const float*)d_in[9];
  const float* fuse_W   = (const float*)d_in[10];
  const float* fuse_b   = (const float*)d_in[11];
  const float* lift_W   = (const float*)d_in[12];
  const float* lift_b   = (const float*)d_in[13];
  const float* phim_W1  = (const float*)d_in[14];
  const float* phim_b1  = (const float*)d_in[15];
  const float* phim_W2  = (const float*)d_in[16];
  const float* phim_b2  = (const float*)d_in[17];
  const float* phix_W1  = (const float*)d_in[18];
  const float* phix_b1  = (const float*)d_in[19];
  const float* phix_W2  = (const float*)d_in[20];
  const float* phix_b2  = (const float*)d_in[21];
  const float* psim_W1  = (const float*)d_in[22];
  const float* psim_b1  = (const float*)d_in[23];
  const float* psim_W2  = (const float*)d_in[24];
  const float* psim_b2  = (const float*)d_in[25];
  const float* updh_W1  = (const float*)d_in[26];
  const float* updh_b1  = (const float*)d_in[27];
  const float* updh_W2  = (const float*)d_in[28];
  const float* updh_b2  = (const float*)d_in[29];
  const float* ln_g     = (const float*)d_in[30];
  const float* ln_b     = (const float*)d_in[31];
  const float* head_W   = (const float*)d_in[32];
  const float* head_b   = (const float*)d_in[33];
  const int*   src      = (const int*)d_in[34];
  const int*   dst      = (const int*)d_in[35];
  const int*   ngraph   = (const int*)d_in[36];
  float* out = (float*)d_out;

  char* p = (char*)d_ws;
  auto carve = [&](size_t bytes) -> char* {
    char* r = p; p += (bytes + 255) & ~(size_t)255; return r;
  };
  float*          h     = (float*)carve((size_t)NN*HID*4);
  unsigned short* hbf   = (unsigned short*)carve((size_t)NN*HID*2);
  float*          xpos  = (float*)carve((size_t)NN*3*4);
  int*            ie    = (int*)carve((size_t)NE*4);
  float*          tabA  = (float*)carve((size_t)KA*HID*4);
  float*          tabC  = (float*)carve((size_t)KC*HID*4);
  unsigned short* tabE  = (unsigned short*)carve((size_t)KE*HID*2);
  unsigned short* rbfb  = (unsigned short*)carve((size_t)NE*RBFK*2);
  float*          rij   = (float*)carve((size_t)NE*3*4);
  float*          gate  = (float*)carve((size_t)NE*4);
  unsigned short* pmbf  = (unsigned short*)carve((size_t)NN*HID*2);
  size_t hg_bytes = (size_t)NG*HID*4 + (size_t)NG*4;
  float*          hg    = (float*)carve(hg_bytes);
  float*          cnt   = hg + (size_t)NG*HID;
  unsigned short* buf0  = (unsigned short*)carve((size_t)NE*HID*2);
  unsigned short* buf1  = (unsigned short*)carve((size_t)NE*HID*2);
  unsigned short* buf2  = (unsigned short*)carve((size_t)NE*HID*2);
  // CSR
  int* deg      = (int*)carve(10240*4);
  int* cursor   = (int*)carve(10240*4);
  int* rowstart = (int*)carve(10241*4);
  int* eids     = (int*)carve((size_t)NE*4);
  // transposed bf16 weights
  unsigned short* wCat   = (unsigned short*)carve((size_t)NDEP*512*CATP*2);
  unsigned short* wPhim2 = (unsigned short*)carve((size_t)NDEP*HID*HID*2);
  unsigned short* wPhix1 = (unsigned short*)carve((size_t)NDEP*HID*HID*2);
  unsigned short* wPsim2 = (unsigned short*)carve((size_t)NDEP*HID*HID*2);
  unsigned short* wUpd1  = (unsigned short*)carve((size_t)NDEP*HID*512*2);
  unsigned short* wUpd2  = (unsigned short*)carve((size_t)NDEP*HID*HID*2);

  // ---- weight conversion ----
  convw_cat<<<dim3(CATP/32, 4, NDEP), 256, 0, stream>>>(phim_W1, wCat, 0);
  convw_cat<<<dim3(CATP/32, 4, NDEP), 256, 0, stream>>>(psim_W1, wCat, 256);
  convw_plain<<<dim3(8, 4, NDEP), 256, 0, stream>>>(phim_W2, wPhim2, 256);
  convw_plain<<<dim3(8, 4, NDEP), 256, 0, stream>>>(phix_W1, wPhix1, 256);
  convw_plain<<<dim3(8, 4, NDEP), 256, 0, stream>>>(psim_W2, wPsim2, 256);
  convw_plain<<<dim3(8, 4, NDEP), 256, 0, stream>>>(updh_W2, wUpd2, 256);
  convw_plain<<<dim3(16, 4, NDEP), 256, 0, stream>>>(updh_W1, wUpd1, 512);

  tables_kernel<<<KA + KC + KE, 256, 0, stream>>>(atom_W, charge_W, bond_W, fuse_W, fuse_b,
                                                  lift_W, lift_b, tabA, tabC, tabE);
  node_init_kernel<<<NN, 256, 0, stream>>>(a_t, c_t, g_a, g_c, x_t, tabA, tabC, h, hbf, xpos);
  edge_init_kernel<<<(NE + 255)/256, 256, 0, stream>>>(e_t, g_e, ie);

  // ---- CSR build ----
  hipMemsetAsync(deg, 0, 10240*4, stream);
  hist_kernel<<<(NE + 255)/256, 256, 0, stream>>>(dst, deg);
  scan_kernel<<<1, 1024, 0, stream>>>(deg, rowstart, cursor);
  fill_kernel<<<(NE + 255)/256, 256, 0, stream>>>(dst, cursor, eids);
  sortrows_kernel<<<(NN + 255)/256, 256, 0, stream>>>(rowstart, eids);

  dim3 gridCat(4, NE/128);
  dim3 gridE(2, NE/128);
  dim3 gridN(2, (NN + 127)/128);

  for (int d = 0; d < NDEP; ++d) {
    const float* pb1m = phim_b1 + (size_t)d*HID;
    const float* pb2m = phim_b2 + (size_t)d*HID;
    const float* pxb1 = phix_b1 + (size_t)d*HID;
    const float* pxW2 = phix_W2 + (size_t)d*HID;
    const float* pxb2 = phix_b2 + (size_t)d;
    const float* psb1 = psim_b1 + (size_t)d*HID;
    const float* psb2 = psim_b2 + (size_t)d*HID;
    const float* pub1 = updh_b1 + (size_t)d*HID;
    const float* pub2 = updh_b2 + (size_t)d*HID;

    rbf_kernel<<<(NE + 255)/256, 256, 0, stream>>>(xpos, src, dst, rij, rbfb);

    // c1 (buf0), ps1 (buf1) = silu(cat @ [phim_W1 ; psim_W1] + b)
    mfma_gemm<1, true, false><<<gridCat, 256, 0, stream>>>(
        nullptr, rbfb, wCat + (size_t)d*512*CATP, pb1m, psb1, buf0, buf1, NE, CATP,
        hbf, tabE, src, dst, ie, nullptr, nullptr);
    // m (buf2) = silu(c1 @ phim_W2 + b2)
    mfma_gemm<0, true, false><<<gridE, 256, 0, stream>>>(
        buf0, nullptr, wPhim2 + (size_t)d*HID*HID, pb2m, nullptr, buf2, nullptr, NE, HID,
        nullptr, nullptr, nullptr, nullptr, nullptr, nullptr, nullptr);
    // pm (buf0) = silu(ps1 @ psim_W2 + b2)
    mfma_gemm<0, true, false><<<gridE, 256, 0, stream>>>(
        buf1, nullptr, wPsim2 + (size_t)d*HID*HID, psb2, nullptr, buf0, nullptr, NE, HID,
        nullptr, nullptr, nullptr, nullptr, nullptr, nullptr, nullptr);
    // gate = silu(m @ phix_W1 + b1) @ phix_W2   (bias b2 added at use)
    hipMemsetAsync(gate, 0, (size_t)NE*4, stream);
    mfma_gemm<0, false, true><<<gridE, 256, 0, stream>>>(
        buf2, nullptr, wPhix1 + (size_t)d*HID*HID, pxb1, nullptr, nullptr, nullptr, NE, HID,
        nullptr, nullptr, nullptr, nullptr, nullptr, pxW2, gate);
    // pm_sum -> pmbf ; x += dx
    gather_pm_dx<<<NN, 256, 0, stream>>>(buf0, gate, rij, rowstart, eids, pxb2, pmbf, xpos);
    // u1 (buf1) = silu([h, pm] @ updh_W1 + b1)
    mfma_gemm<2, true, false><<<gridN, 256, 0, stream>>>(
        hbf, pmbf, wUpd1 + (size_t)d*HID*512, pub1, nullptr, buf1, nullptr, NN, 512,
        nullptr, nullptr, nullptr, nullptr, nullptr, nullptr, nullptr);
    // u (buf2) = u1 @ updh_W2 + b2
    mfma_gemm<0, false, false><<<gridN, 256, 0, stream>>>(
        buf1, nullptr, wUpd2 + (size_t)d*HID*HID, pub2, nullptr, buf2, nullptr, NN, HID,
        nullptr, nullptr, nullptr, nullptr, nullptr, nullptr, nullptr);
    ln_kernel<<<NN, 256, 0, stream>>>(h, hbf, buf2, ln_g + (size_t)d*HID, ln_b + (size_t)d*HID);
  }

  hipMemsetAsync(hg, 0, hg_bytes, stream);
  graph_acc_kernel<<<NN, 256, 0, stream>>>(h, ngraph, hg, cnt);
  head_kernel<<<1, 64, 0, stream>>>(hg, cnt, head_W, head_b, out);
}

// Round 4
// 2255.758 us; speedup vs baseline: 4.6130x; 1.1559x over previous
//
#include <hip/hip_runtime.h>
#include <math.h>

#define NN   10000
#define NE   80000
#define NG   64
#define HID  256
#define RBFK 16
#define NDEP 6
#define KA   16
#define KC   6
#define KE   5
#define DE   85
#define CATW 784
#define CATP 832   // padded to multiple of 64

typedef __attribute__((ext_vector_type(8))) short bf16x8;
typedef __attribute__((ext_vector_type(4))) float f32x4;

static __device__ __forceinline__ float silu_f(float v) { return v / (1.0f + expf(-v)); }

static __device__ __forceinline__ unsigned short f2bf(float f) {
  union { float f; unsigned int u; } v; v.f = f;
  unsigned int r = v.u + 0x7fff + ((v.u >> 16) & 1);
  return (unsigned short)(r >> 16);
}
static __device__ __forceinline__ float bf2f(unsigned short h) {
  union { unsigned int u; float f; } v; v.u = ((unsigned int)h) << 16;
  return v.f;
}

static __device__ __forceinline__ void gload16(const void* g, void* l) {
  __builtin_amdgcn_global_load_lds((const __attribute__((address_space(1))) unsigned int*)g,
                                   (__attribute__((address_space(3))) unsigned int*)l, 16, 0, 0);
}

// ---------------- LDS-tiled weight transpose-convert ----------------
__global__ void convw_plain(const float* __restrict__ W, unsigned short* __restrict__ Wt, int K) {
  __shared__ float T[32][65];
  int k0 = blockIdx.x * 32, n0 = blockIdx.y * 64, d = blockIdx.z;
  int tid = threadIdx.x;
  int nn = tid & 63, kr = tid >> 6;
  const float* Wd = W + (size_t)d * K * 256;
#pragma unroll
  for (int i = 0; i < 8; ++i) {
    int k = kr + i * 4;
    T[k][nn] = Wd[(size_t)(k0 + k) * 256 + n0 + nn];
  }
  __syncthreads();
  unsigned short* Wtd = Wt + (size_t)d * 256 * K;
  int kk = tid & 31, nr = tid >> 5;
#pragma unroll
  for (int i = 0; i < 8; ++i) {
    int n = nr + i * 8;
    Wtd[(size_t)(n0 + n) * K + k0 + kk] = f2bf(T[kk][n]);
  }
}

// cat: W [D][784][256] f32 -> Wt [D][512][832] bf16 rows [ro, ro+256)
// permuted k-order: [h_dst 0..511 | e_emb 512..767 | rbf 768..783 | pad..831]
__global__ void convw_cat(const float* __restrict__ W, unsigned short* __restrict__ Wt, int ro) {
  __shared__ float T[32][65];
  int k0 = blockIdx.x * 32, n0 = blockIdx.y * 64, d = blockIdx.z;
  int tid = threadIdx.x;
  int nn = tid & 63, kr = tid >> 6;
  const float* Wd = W + (size_t)d * CATW * 256;
#pragma unroll
  for (int i = 0; i < 8; ++i) {
    int k = k0 + kr + i * 4;
    int ko = (k < 512) ? k : (k < 768 ? k + 16 : (k < 784 ? k - 256 : -1));
    T[kr + i*4][nn] = (ko >= 0) ? Wd[(size_t)ko * 256 + n0 + nn] : 0.f;
  }
  __syncthreads();
  unsigned short* Wtd = Wt + (size_t)d * 512 * CATP;
  int kk = tid & 31, nr = tid >> 5;
#pragma unroll
  for (int i = 0; i < 8; ++i) {
    int n = nr + i * 8;
    Wtd[(size_t)(ro + n0 + n) * CATP + k0 + kk] = f2bf(T[kk][n]);
  }
}

// ---------------- tables (27 blocks) ----------------
__global__ void tables_kernel(const float* __restrict__ atom_W, const float* __restrict__ charge_W,
                              const float* __restrict__ bond_W, const float* __restrict__ fuse_W,
                              const float* __restrict__ fuse_b, const float* __restrict__ lift_W,
                              const float* __restrict__ lift_b,
                              float* __restrict__ tabA, float* __restrict__ tabC,
                              unsigned short* __restrict__ tabE) {
  int r = blockIdx.x, k = threadIdx.x;
  if (r < KA) {
    float s = 0.f;
    for (int d = 0; d < DE; ++d) s += atom_W[r*DE + d] * fuse_W[d*HID + k];
    tabA[r*HID + k] = s + fuse_b[k];
  } else if (r < KA + KC) {
    int rr = r - KA;
    float s = 0.f;
    for (int d = 0; d < DE; ++d) s += charge_W[rr*DE + d] * fuse_W[(DE + d)*HID + k];
    tabC[rr*HID + k] = s;
  } else {
    int rr = r - KA - KC;
    float s = 0.f;
    for (int d = 0; d < DE; ++d) s += bond_W[rr*DE + d] * lift_W[d*HID + k];
    tabE[rr*HID + k] = f2bf(s + lift_b[k]);
  }
}

// ---------------- node / edge init ----------------
__global__ void node_init_kernel(const float* __restrict__ a_t, const float* __restrict__ c_t,
                                 const float* __restrict__ g_a, const float* __restrict__ g_c,
                                 const float* __restrict__ x_t, const float* __restrict__ tabA,
                                 const float* __restrict__ tabC, float* __restrict__ h,
                                 unsigned short* __restrict__ hbf, float* __restrict__ x) {
  int n = blockIdx.x;
  __shared__ int s_ia, s_ic;
  if (threadIdx.x == 0) {
    float best = -1e30f; int bi = 0;
    for (int j = 0; j < KA; ++j) {
      float v = logf(fmaxf(a_t[n*KA + j], 1e-12f)) + g_a[n*KA + j];
      if (v > best) { best = v; bi = j; }
    }
    s_ia = bi;
  }
  if (threadIdx.x == 1) {
    float best = -1e30f; int bi = 0;
    for (int j = 0; j < KC; ++j) {
      float v = logf(fmaxf(c_t[n*KC + j], 1e-12f)) + g_c[n*KC + j];
      if (v > best) { best = v; bi = j; }
    }
    s_ic = bi;
  }
  __syncthreads();
  int k = threadIdx.x;
  float v = tabA[s_ia*HID + k] + tabC[s_ic*HID + k];
  h[n*HID + k] = v;
  hbf[n*HID + k] = f2bf(v);
  if (k < 3) x[n*3 + k] = x_t[n*3 + k];
}

__global__ void edge_init_kernel(const float* __restrict__ e_t, const float* __restrict__ g_e,
                                 int* __restrict__ ie) {
  int e = blockIdx.x * blockDim.x + threadIdx.x;
  if (e >= NE) return;
  float best = -1e30f; int bi = 0;
  for (int j = 0; j < KE; ++j) {
    float v = logf(fmaxf(e_t[e*KE + j], 1e-12f)) + g_e[e*KE + j];
    if (v > best) { best = v; bi = j; }
  }
  ie[e] = bi;
}

// ---------------- CSR build ----------------
__global__ void hist_kernel(const int* __restrict__ dst, int* __restrict__ deg) {
  int e = blockIdx.x * 256 + threadIdx.x;
  if (e < NE) atomicAdd(&deg[dst[e]], 1);
}

__global__ void scan_kernel(const int* __restrict__ deg, int* __restrict__ rowstart,
                            int* __restrict__ cursor) {
  __shared__ int tmp[1024];
  int t = threadIdx.x;
  int base = t * 10;
  int local[10];
  int s = 0;
#pragma unroll
  for (int i = 0; i < 10; ++i) { local[i] = deg[base + i]; s += local[i]; }
  tmp[t] = s;
  __syncthreads();
  for (int off = 1; off < 1024; off <<= 1) {
    int v = (t >= off) ? tmp[t - off] : 0;
    __syncthreads();
    tmp[t] += v;
    __syncthreads();
  }
  int run = (t == 0) ? 0 : tmp[t - 1];
#pragma unroll
  for (int i = 0; i < 10; ++i) {
    rowstart[base + i] = run; cursor[base + i] = run; run += local[i];
  }
  if (t == 1023) rowstart[10240] = run;
}

__global__ void fill_kernel(const int* __restrict__ dst, int* __restrict__ cursor,
                            int* __restrict__ eids) {
  int e = blockIdx.x * 256 + threadIdx.x;
  if (e >= NE) return;
  int pos = atomicAdd(&cursor[dst[e]], 1);
  eids[pos] = e;
}

__global__ void sortrows_kernel(const int* __restrict__ rowstart, int* __restrict__ eids) {
  int n = blockIdx.x * 256 + threadIdx.x;
  if (n >= NN) return;
  int s = rowstart[n], e = rowstart[n + 1];
  for (int i = s + 1; i < e; ++i) {
    int v = eids[i]; int j = i - 1;
    while (j >= s && eids[j] > v) { eids[j + 1] = eids[j]; --j; }
    eids[j + 1] = v;
  }
}

// ---------------- per-depth: rij + rbf(bf16) ----------------
__global__ void rbf_kernel(const float* __restrict__ x, const int* __restrict__ srcp,
                           const int* __restrict__ dstp, float* __restrict__ rij,
                           unsigned short* __restrict__ rbfb) {
  int e = blockIdx.x * blockDim.x + threadIdx.x;
  if (e >= NE) return;
  int s = srcp[e], d = dstp[e];
  float r0 = x[d*3+0] - x[s*3+0];
  float r1 = x[d*3+1] - x[s*3+1];
  float r2 = x[d*3+2] - x[s*3+2];
  rij[e*3+0] = r0; rij[e*3+1] = r1; rij[e*3+2] = r2;
  float dist = sqrtf(r0*r0 + r1*r1 + r2*r2);
#pragma unroll
  for (int k = 0; k < RBFK; ++k) {
    float c = (10.0f/15.0f) * (float)k;
    float z = (dist - c) / (0.625f + 1e-12f);
    rbfb[e*RBFK + k] = f2bf(expf(-0.5f * z * z));
  }
}

// ---------------- MFMA bf16 GEMM (global_load_lds staging, BK=64, XOR swizzle) ----------------
// MODE 0: A bf16 [M][256]
// MODE 1: A = cat(e) = [h[dst] | h[src] | tabE[ie] | rbf | pad] (Kp=832, N=512 dual-output)
// MODE 2: A = [hbf | pmbf] (Kp=512)
// GATE:   no C store; gate[row] += sum_col silu(acc+b1[col]) * gw2[col]
template<int MODE, bool SILU, bool GATE>
__global__ __launch_bounds__(256) void mfma_gemm(
    const unsigned short* __restrict__ A, const unsigned short* __restrict__ A2,
    const unsigned short* __restrict__ Wt,
    const float* __restrict__ bias, const float* __restrict__ bias2,
    unsigned short* __restrict__ C, unsigned short* __restrict__ C2,
    int M, int Kp,
    const unsigned short* __restrict__ hbf, const unsigned short* __restrict__ tabE,
    const int* __restrict__ srcp, const int* __restrict__ dstp, const int* __restrict__ iep,
    const unsigned short* __restrict__ rbfb, const unsigned short* __restrict__ zpad,
    const float* __restrict__ gw2, float* __restrict__ gout) {
  __shared__ unsigned short As[128 * 64];   // row-major [128][64], XOR-swizzled storage
  __shared__ unsigned short Bs[128 * 64];
  const int tid = threadIdx.x;
  const int bn = blockIdx.x * 128;
  const int bm = blockIdx.y * 128;
  const int lane = tid & 63;
  const int w = tid >> 6;
  const int wr = w >> 1, wc = w & 1;
  const int subrow = lane >> 3;                 // 0..7
  const int kd = 8 * ((lane & 7) ^ subrow);     // pre-swizzled data k-offset (elems)

  // per-thread staged rows (4 issues per wave)
  const unsigned short* baseB[4];
  const unsigned short* baseA[4];
  const unsigned short* baseA2[4];
  const unsigned short* baseE[4];
  const unsigned short* baseR[4];
#pragma unroll
  for (int q = 0; q < 4; ++q) {
    int r = w * 32 + q * 8 + subrow;
    baseB[q] = Wt + (size_t)(bn + r) * Kp;
    int m = bm + r;
    int mc = (m < M) ? m : (M - 1);
    if (MODE == 1) {
      baseA[q]  = hbf + (size_t)dstp[m] * 256;
      baseA2[q] = hbf + (size_t)srcp[m] * 256;
      baseE[q]  = tabE + (size_t)iep[m] * 256;
      baseR[q]  = rbfb + (size_t)m * RBFK;
    } else {
      baseA[q]  = A + (size_t)mc * 256;
      baseA2[q] = (MODE == 2) ? (A2 + (size_t)mc * 256) : nullptr;
    }
  }

  f32x4 acc[4][4] = {};

  for (int k0 = 0; k0 < Kp; k0 += 64) {
#pragma unroll
    for (int q = 0; q < 4; ++q) {
      char* ldsA = (char*)As + w * 4096 + q * 1024;
      char* ldsB = (char*)Bs + w * 4096 + q * 1024;
      const unsigned short* gp;
      if (MODE == 0) {
        gp = baseA[q] + k0 + kd;
      } else if (MODE == 1) {
        if (k0 < 256)      gp = baseA[q] + k0 + kd;
        else if (k0 < 512) gp = baseA2[q] + (k0 - 256) + kd;
        else if (k0 < 768) gp = baseE[q] + (k0 - 512) + kd;
        else               gp = (kd < RBFK) ? (baseR[q] + kd) : zpad;
      } else {
        gp = (k0 < 256) ? (baseA[q] + k0 + kd) : (baseA2[q] + (k0 - 256) + kd);
      }
      gload16(gp, ldsA);
      gload16(baseB[q] + k0 + kd, ldsB);
    }
    __syncthreads();
#pragma unroll
    for (int ks = 0; ks < 2; ++ks) {
      const int kb = (ks * 64 + ((lane >> 4) << 4)) ^ ((lane & 7) << 4);
      bf16x8 af[4], bfv[4];
#pragma unroll
      for (int i = 0; i < 4; ++i)
        af[i] = *(const bf16x8*)((const char*)As + (wr*64 + i*16 + (lane & 15)) * 128 + kb);
#pragma unroll
      for (int j = 0; j < 4; ++j)
        bfv[j] = *(const bf16x8*)((const char*)Bs + (wc*64 + j*16 + (lane & 15)) * 128 + kb);
#pragma unroll
      for (int i = 0; i < 4; ++i)
#pragma unroll
        for (int j = 0; j < 4; ++j)
          acc[i][j] = __builtin_amdgcn_mfma_f32_16x16x32_bf16(af[i], bfv[j], acc[i][j], 0, 0, 0);
    }
    __syncthreads();
  }

  if (GATE) {
    float bcol[4], wcol[4];
#pragma unroll
    for (int j = 0; j < 4; ++j) {
      int col = bn + wc*64 + j*16 + (lane & 15);
      bcol[j] = bias[col];
      wcol[j] = gw2[col];
    }
#pragma unroll
    for (int i = 0; i < 4; ++i) {
#pragma unroll
      for (int q = 0; q < 4; ++q) {
        float lsum = 0.f;
#pragma unroll
        for (int j = 0; j < 4; ++j)
          lsum += silu_f(acc[i][j][q] + bcol[j]) * wcol[j];
        lsum += __shfl_xor(lsum, 1, 64);
        lsum += __shfl_xor(lsum, 2, 64);
        lsum += __shfl_xor(lsum, 4, 64);
        lsum += __shfl_xor(lsum, 8, 64);
        if ((lane & 15) == 0) {
          int row = bm + wr*64 + i*16 + ((lane >> 4) << 2) + q;
          if (row < M) atomicAdd(&gout[row], lsum);
        }
      }
    }
    return;
  }

  const float* biasw = bias;
  unsigned short* Cw = C;
  int cb = bn;
  if (MODE == 1 && bn >= 256) { biasw = bias2; Cw = C2; cb = bn - 256; }

  const int colbase = cb + wc*64 + (lane & 15);
#pragma unroll
  for (int j = 0; j < 4; ++j) {
    int col = colbase + j*16;
    float bv = biasw[col];
#pragma unroll
    for (int i = 0; i < 4; ++i) {
      int row0 = bm + wr*64 + i*16 + (lane >> 4) * 4;
#pragma unroll
      for (int q = 0; q < 4; ++q) {
        int row = row0 + q;
        if (row < M) {
          float v = acc[i][j][q] + bv;
          if (SILU) v = silu_f(v);
          Cw[(size_t)row*256 + col] = f2bf(v);
        }
      }
    }
  }
}

// ---------------- CSR gather: pm_sum (bf16 out) + dx + x update ----------------
__global__ void gather_pm_dx(const unsigned short* __restrict__ pm, const float* __restrict__ gate,
                             const float* __restrict__ rij, const int* __restrict__ rowstart,
                             const int* __restrict__ eids, const float* __restrict__ gb2,
                             unsigned short* __restrict__ pmbf, float* __restrict__ x) {
  int n = blockIdx.x, k = threadIdx.x;
  int s = rowstart[n], e1 = rowstart[n + 1];
  float acc = 0.f, dx = 0.f;
  float b2 = gb2[0];
  for (int t = s; t < e1; ++t) {
    int e = eids[t];
    acc += bf2f(pm[(size_t)e*HID + k]);
    if (k < 3) dx += rij[e*3 + k] * (gate[e] + b2);
  }
  pmbf[(size_t)n*HID + k] = f2bf(acc);
  if (k < 3) x[n*3 + k] += dx;
}

// ---------------- LayerNorm(h + u) ----------------
__global__ void ln_kernel(float* __restrict__ h, unsigned short* __restrict__ hbf,
                          const unsigned short* __restrict__ u,
                          const float* __restrict__ g, const float* __restrict__ b) {
  int n = blockIdx.x;
  int k = threadIdx.x;
  int lane = k & 63, wv = k >> 6;
  float z = h[(size_t)n*HID + k] + bf2f(u[(size_t)n*HID + k]);
  __shared__ float red[4];
  __shared__ float s_mu, s_rstd;
  float s = z;
#pragma unroll
  for (int off = 32; off > 0; off >>= 1) s += __shfl_down(s, off, 64);
  if (lane == 0) red[wv] = s;
  __syncthreads();
  if (k == 0) s_mu = (red[0] + red[1] + red[2] + red[3]) * (1.0f/HID);
  __syncthreads();
  float d = z - s_mu;
  float s2 = d * d;
#pragma unroll
  for (int off = 32; off > 0; off >>= 1) s2 += __shfl_down(s2, off, 64);
  if (lane == 0) red[wv] = s2;
  __syncthreads();
  if (k == 0) s_rstd = 1.0f / sqrtf((red[0] + red[1] + red[2] + red[3]) * (1.0f/HID) + 1e-5f);
  __syncthreads();
  float o = d * s_rstd * g[k] + b[k];
  h[(size_t)n*HID + k] = o;
  hbf[(size_t)n*HID + k] = f2bf(o);
}

// ---------------- readout ----------------
__global__ void graph_acc_kernel(const float* __restrict__ h, const int* __restrict__ ng,
                                 float* __restrict__ hg, float* __restrict__ cnt) {
  int n = blockIdx.x, k = threadIdx.x;
  int g = ng[n];
  atomicAdd(&hg[(size_t)g*HID + k], h[(size_t)n*HID + k]);
  if (k == 0) atomicAdd(&cnt[g], 1.0f);
}

__global__ void head_kernel(const float* __restrict__ hg, const float* __restrict__ cnt,
                            const float* __restrict__ head_W, const float* __restrict__ head_b,
                            float* __restrict__ out) {
  int g = threadIdx.x;
  if (g >= NG) return;
  float dot = 0.f;
  for (int k = 0; k < HID; ++k) dot += hg[(size_t)g*HID + k] * head_W[k];
  float c = fmaxf(cnt[g], 1.0f);
  float v = (dot / c + head_b[0]) * 0.5f;
  out[g] = 1.0f / (1.0f + expf(-v));
}

extern "C" void kernel_launch(void* const* d_in, const int* in_sizes, int n_in,
                              void* d_out, int out_size, void* d_ws, size_t ws_size,
                              hipStream_t stream) {
  (void)in_sizes; (void)n_in; (void)out_size; (void)ws_size;
  const float* a_t      = (const float*)d_in[0];
  const float* c_t      = (const float*)d_in[1];
  const float* e_t      = (const float*)d_in[2];
  const float* x_t      = (const float*)d_in[3];
  const float* g_a      = (const float*)d_in[4];
  const float* g_c      = (const float*)d_in[5];
  const float* g_e      = (const float*)d_in[6];
  const float* atom_W   = (const float*)d_in[7];
  const float* charge_W = (const float*)d_in[8];
  const float* bond_W   = (const float*)d_in[9];
  const float* fuse_W   = (const float*)d_in[10];
  const float* fuse_b   = (const float*)d_in[11];
  const float* lift_W   = (const float*)d_in[12];
  const float* lift_b   = (const float*)d_in[13];
  const float* phim_W1  = (const float*)d_in[14];
  const float* phim_b1  = (const float*)d_in[15];
  const float* phim_W2  = (const float*)d_in[16];
  const float* phim_b2  = (const float*)d_in[17];
  const float* phix_W1  = (const float*)d_in[18];
  const float* phix_b1  = (const float*)d_in[19];
  const float* phix_W2  = (const float*)d_in[20];
  const float* phix_b2  = (const float*)d_in[21];
  const float* psim_W1  = (const float*)d_in[22];
  const float* psim_b1  = (const float*)d_in[23];
  const float* psim_W2  = (const float*)d_in[24];
  const float* psim_b2  = (const float*)d_in[25];
  const float* updh_W1  = (const float*)d_in[26];
  const float* updh_b1  = (const float*)d_in[27];
  const float* updh_W2  = (const float*)d_in[28];
  const float* updh_b2  = (const float*)d_in[29];
  const float* ln_g     = (const float*)d_in[30];
  const float* ln_b     = (const float*)d_in[31];
  const float* head_W   = (const float*)d_in[32];
  const float* head_b   = (const float*)d_in[33];
  const int*   src      = (const int*)d_in[34];
  const int*   dst      = (const int*)d_in[35];
  const int*   ngraph   = (const int*)d_in[36];
  float* out = (float*)d_out;

  char* p = (char*)d_ws;
  auto carve = [&](size_t bytes) -> char* {
    char* r = p; p += (bytes + 255) & ~(size_t)255; return r;
  };
  float*          h     = (float*)carve((size_t)NN*HID*4);
  unsigned short* hbf   = (unsigned short*)carve((size_t)NN*HID*2);
  float*          xpos  = (float*)carve((size_t)NN*3*4);
  int*            ie    = (int*)carve((size_t)NE*4);
  float*          tabA  = (float*)carve((size_t)KA*HID*4);
  float*          tabC  = (float*)carve((size_t)KC*HID*4);
  unsigned short* tabE  = (unsigned short*)carve((size_t)KE*HID*2);
  unsigned short* rbfb  = (unsigned short*)carve((size_t)NE*RBFK*2);
  float*          rij   = (float*)carve((size_t)NE*3*4);
  float*          gate  = (float*)carve((size_t)NE*4);
  unsigned short* pmbf  = (unsigned short*)carve((size_t)NN*HID*2);
  unsigned short* zpad  = (unsigned short*)carve(256);
  size_t hg_bytes = (size_t)NG*HID*4 + (size_t)NG*4;
  float*          hg    = (float*)carve(hg_bytes);
  float*          cnt   = hg + (size_t)NG*HID;
  unsigned short* buf0  = (unsigned short*)carve((size_t)NE*HID*2);
  unsigned short* buf1  = (unsigned short*)carve((size_t)NE*HID*2);
  unsigned short* buf2  = (unsigned short*)carve((size_t)NE*HID*2);
  // CSR
  int* deg      = (int*)carve(10240*4);
  int* cursor   = (int*)carve(10240*4);
  int* rowstart = (int*)carve(10241*4);
  int* eids     = (int*)carve((size_t)NE*4);
  // transposed bf16 weights
  unsigned short* wCat   = (unsigned short*)carve((size_t)NDEP*512*CATP*2);
  unsigned short* wPhim2 = (unsigned short*)carve((size_t)NDEP*HID*HID*2);
  unsigned short* wPhix1 = (unsigned short*)carve((size_t)NDEP*HID*HID*2);
  unsigned short* wPsim2 = (unsigned short*)carve((size_t)NDEP*HID*HID*2);
  unsigned short* wUpd1  = (unsigned short*)carve((size_t)NDEP*HID*512*2);
  unsigned short* wUpd2  = (unsigned short*)carve((size_t)NDEP*HID*HID*2);

  // ---- weight conversion ----
  convw_cat<<<dim3(CATP/32, 4, NDEP), 256, 0, stream>>>(phim_W1, wCat, 0);
  convw_cat<<<dim3(CATP/32, 4, NDEP), 256, 0, stream>>>(psim_W1, wCat, 256);
  convw_plain<<<dim3(8, 4, NDEP), 256, 0, stream>>>(phim_W2, wPhim2, 256);
  convw_plain<<<dim3(8, 4, NDEP), 256, 0, stream>>>(phix_W1, wPhix1, 256);
  convw_plain<<<dim3(8, 4, NDEP), 256, 0, stream>>>(psim_W2, wPsim2, 256);
  convw_plain<<<dim3(8, 4, NDEP), 256, 0, stream>>>(updh_W2, wUpd2, 256);
  convw_plain<<<dim3(16, 4, NDEP), 256, 0, stream>>>(updh_W1, wUpd1, 512);
  hipMemsetAsync(zpad, 0, 256, stream);

  tables_kernel<<<KA + KC + KE, 256, 0, stream>>>(atom_W, charge_W, bond_W, fuse_W, fuse_b,
                                                  lift_W, lift_b, tabA, tabC, tabE);
  node_init_kernel<<<NN, 256, 0, stream>>>(a_t, c_t, g_a, g_c, x_t, tabA, tabC, h, hbf, xpos);
  edge_init_kernel<<<(NE + 255)/256, 256, 0, stream>>>(e_t, g_e, ie);

  // ---- CSR build ----
  hipMemsetAsync(deg, 0, 10240*4, stream);
  hist_kernel<<<(NE + 255)/256, 256, 0, stream>>>(dst, deg);
  scan_kernel<<<1, 1024, 0, stream>>>(deg, rowstart, cursor);
  fill_kernel<<<(NE + 255)/256, 256, 0, stream>>>(dst, cursor, eids);
  sortrows_kernel<<<(NN + 255)/256, 256, 0, stream>>>(rowstart, eids);

  dim3 gridCat(4, NE/128);
  dim3 gridE(2, NE/128);
  dim3 gridN(2, (NN + 127)/128);

  for (int d = 0; d < NDEP; ++d) {
    const float* pb1m = phim_b1 + (size_t)d*HID;
    const float* pb2m = phim_b2 + (size_t)d*HID;
    const float* pxb1 = phix_b1 + (size_t)d*HID;
    const float* pxW2 = phix_W2 + (size_t)d*HID;
    const float* pxb2 = phix_b2 + (size_t)d;
    const float* psb1 = psim_b1 + (size_t)d*HID;
    const float* psb2 = psim_b2 + (size_t)d*HID;
    const float* pub1 = updh_b1 + (size_t)d*HID;
    const float* pub2 = updh_b2 + (size_t)d*HID;

    rbf_kernel<<<(NE + 255)/256, 256, 0, stream>>>(xpos, src, dst, rij, rbfb);

    // c1 (buf0), ps1 (buf1) = silu(cat @ [phim_W1 ; psim_W1] + b)
    mfma_gemm<1, true, false><<<gridCat, 256, 0, stream>>>(
        nullptr, nullptr, wCat + (size_t)d*512*CATP, pb1m, psb1, buf0, buf1, NE, CATP,
        hbf, tabE, src, dst, ie, rbfb, zpad, nullptr, nullptr);
    // m (buf2) = silu(c1 @ phim_W2 + b2)
    mfma_gemm<0, true, false><<<gridE, 256, 0, stream>>>(
        buf0, nullptr, wPhim2 + (size_t)d*HID*HID, pb2m, nullptr, buf2, nullptr, NE, HID,
        nullptr, nullptr, nullptr, nullptr, nullptr, nullptr, zpad, nullptr, nullptr);
    // pm (buf0) = silu(ps1 @ psim_W2 + b2)
    mfma_gemm<0, true, false><<<gridE, 256, 0, stream>>>(
        buf1, nullptr, wPsim2 + (size_t)d*HID*HID, psb2, nullptr, buf0, nullptr, NE, HID,
        nullptr, nullptr, nullptr, nullptr, nullptr, nullptr, zpad, nullptr, nullptr);
    // gate = silu(m @ phix_W1 + b1) @ phix_W2   (bias b2 added at use)
    hipMemsetAsync(gate, 0, (size_t)NE*4, stream);
    mfma_gemm<0, false, true><<<gridE, 256, 0, stream>>>(
        buf2, nullptr, wPhix1 + (size_t)d*HID*HID, pxb1, nullptr, nullptr, nullptr, NE, HID,
        nullptr, nullptr, nullptr, nullptr, nullptr, nullptr, zpad, pxW2, gate);
    // pm_sum -> pmbf ; x += dx
    gather_pm_dx<<<NN, 256, 0, stream>>>(buf0, gate, rij, rowstart, eids, pxb2, pmbf, xpos);
    // u1 (buf1) = silu([h, pm] @ updh_W1 + b1)
    mfma_gemm<2, true, false><<<gridN, 256, 0, stream>>>(
        hbf, pmbf, wUpd1 + (size_t)d*HID*512, pub1, nullptr, buf1, nullptr, NN, 512,
        nullptr, nullptr, nullptr, nullptr, nullptr, nullptr, zpad, nullptr, nullptr);
    // u (buf2) = u1 @ updh_W2 + b2
    mfma_gemm<0, false, false><<<gridN, 256, 0, stream>>>(
        buf1, nullptr, wUpd2 + (size_t)d*HID*HID, pub2, nullptr, buf2, nullptr, NN, HID,
        nullptr, nullptr, nullptr, nullptr, nullptr, nullptr, zpad, nullptr, nullptr);
    ln_kernel<<<NN, 256, 0, stream>>>(h, hbf, buf2, ln_g + (size_t)d*HID, ln_b + (size_t)d*HID);
  }

  hipMemsetAsync(hg, 0, hg_bytes, stream);
  graph_acc_kernel<<<NN, 256, 0, stream>>>(h, ngraph, hg, cnt);
  head_kernel<<<1, 64, 0, stream>>>(hg, cnt, head_W, head_b, out);
}